// Round 8
// baseline (598.100 us; speedup 1.0000x reference)
//
#include <hip/hip_runtime.h>
#include <hip/hip_bf16.h>
#include <math.h>

// TransformerBlock fp32 in/out; internal bf16 MFMA compute.
// B=8, N=1024, D=768, H=12, hd=64, HIDDEN=3072, EPS=1e-6
//
// R6 (resubmit; prior round hit GPUAcquisitionTimeout, never measured).
// GEMMs are no-LDS register GEMMs (fragments loaded straight from
// L2-resident operands, reg double-buffer, zero barriers). Theory: R0's
// staged GEMM is LDS-BW-bound (40KB ds_read + 20KB lds-write per K-step vs
// 117cyc MFMA -> 25% MfmaUtil ceiling, matching measured 22%). Operands are
// L2-resident -> staging is pure overhead (guide common-mistake #7).
// attn/pre/ln unchanged from the 356us R0 baseline.

#define DIM 768
#define SEQ 1024
#define BATCH 8
#define NHEAD 12
#define HDIM 64
#define HID 3072
#define MTOK (BATCH * SEQ)  // 8192

typedef __attribute__((ext_vector_type(8))) short short8;
typedef __attribute__((ext_vector_type(4))) short short4v;
typedef __attribute__((ext_vector_type(4))) float floatx4;

__device__ __forceinline__ short f2s(float x) {
  __hip_bfloat16 h = __float2bfloat16(x);
  return __builtin_bit_cast(short, h);
}
__device__ __forceinline__ float s2f(short s) {
  return __bfloat162float(__builtin_bit_cast(__hip_bfloat16, s));
}
__device__ __forceinline__ floatx4 zf4() {
  floatx4 v; v[0] = v[1] = v[2] = v[3] = 0.f; return v;
}
__device__ __forceinline__ float gelu_f(float x) {
  float z = 0.7978845608028654f * (x + 0.044715f * x * x * x);
  float u = __expf(2.f * z);
  return 0.5f * x * (2.f - 2.f / (u + 1.f));
}

// ---------- merged prologue: 4 weight transposes + LN1 in one launch ----------
__global__ __launch_bounds__(256) void pre_kernel(
    const float* __restrict__ w0, short* __restrict__ o0,
    const float* __restrict__ w1, short* __restrict__ o1,
    const float* __restrict__ w2, short* __restrict__ o2,
    const float* __restrict__ w3, short* __restrict__ o3,
    const float* __restrict__ x, const float* __restrict__ ls,
    const float* __restrict__ lb, short* __restrict__ y) {
  const int id = blockIdx.x;
  const int t = threadIdx.x;
  if (id < 6912) {
    __shared__ float tile[32][33];
    const float* in;
    short* out;
    int K, N, tid;
    if (id < 1728)      { in = w0; out = o0; K = DIM; N = 3 * DIM; tid = id; }
    else if (id < 2304) { in = w1; out = o1; K = DIM; N = DIM;     tid = id - 1728; }
    else if (id < 4608) { in = w2; out = o2; K = DIM; N = HID;     tid = id - 2304; }
    else                { in = w3; out = o3; K = HID; N = DIM;     tid = id - 4608; }
    const int ntx = N >> 5;
    const int n0 = (tid % ntx) * 32, k0 = (tid / ntx) * 32;
    const int tx = t & 31, ty = t >> 5;
#pragma unroll
    for (int i = 0; i < 4; ++i)
      tile[ty + i * 8][tx] = in[(size_t)(k0 + ty + i * 8) * N + n0 + tx];
    __syncthreads();
#pragma unroll
    for (int i = 0; i < 4; ++i)
      out[(size_t)(n0 + ty + i * 8) * K + k0 + tx] = f2s(tile[tx][ty + i * 8]);
  } else {
    const int row = id - 6912;
    const float* xr = x + (size_t)row * DIM;
    float v[3];
    float s1 = 0.f, s2 = 0.f;
#pragma unroll
    for (int j = 0; j < 3; ++j) {
      v[j] = xr[t + j * 256];
      s1 += v[j];
      s2 += v[j] * v[j];
    }
#pragma unroll
    for (int off = 32; off; off >>= 1) {
      s1 += __shfl_down(s1, off, 64);
      s2 += __shfl_down(s2, off, 64);
    }
    __shared__ float r1[4], r2[4], bc[2];
    const int wave = t >> 6, lane = t & 63;
    if (lane == 0) { r1[wave] = s1; r2[wave] = s2; }
    __syncthreads();
    if (t == 0) {
      float S1 = r1[0] + r1[1] + r1[2] + r1[3];
      float S2 = r2[0] + r2[1] + r2[2] + r2[3];
      float mu = S1 * (1.0f / DIM);
      float var = S2 * (1.0f / DIM) - mu * mu;
      bc[0] = mu;
      bc[1] = rsqrtf(fmaxf(var, 0.f) + 1e-6f);
    }
    __syncthreads();
    const float mu = bc[0], rstd = bc[1];
#pragma unroll
    for (int j = 0; j < 3; ++j) {
      const int idx = t + j * 256;
      y[(size_t)row * DIM + idx] = f2s((v[j] - mu) * rstd * ls[idx] + lb[idx]);
    }
  }
}

// ---------- LayerNorm (standalone, for LN2) ----------
__global__ __launch_bounds__(256) void ln_kernel(const float* __restrict__ x,
                                                 const float* __restrict__ scale,
                                                 const float* __restrict__ bias,
                                                 short* __restrict__ y) {
  const int row = blockIdx.x;
  const int t = threadIdx.x;
  const float* xr = x + (size_t)row * DIM;
  float v[3];
  float s1 = 0.f, s2 = 0.f;
#pragma unroll
  for (int j = 0; j < 3; ++j) {
    v[j] = xr[t + j * 256];
    s1 += v[j];
    s2 += v[j] * v[j];
  }
#pragma unroll
  for (int off = 32; off; off >>= 1) {
    s1 += __shfl_down(s1, off, 64);
    s2 += __shfl_down(s2, off, 64);
  }
  __shared__ float r1[4], r2[4], bc[2];
  const int wave = t >> 6, lane = t & 63;
  if (lane == 0) { r1[wave] = s1; r2[wave] = s2; }
  __syncthreads();
  if (t == 0) {
    float S1 = r1[0] + r1[1] + r1[2] + r1[3];
    float S2 = r2[0] + r2[1] + r2[2] + r2[3];
    float mu = S1 * (1.0f / DIM);
    float var = S2 * (1.0f / DIM) - mu * mu;
    bc[0] = mu;
    bc[1] = rsqrtf(fmaxf(var, 0.f) + 1e-6f);
  }
  __syncthreads();
  const float mu = bc[0], rstd = bc[1];
#pragma unroll
  for (int j = 0; j < 3; ++j) {
    const int idx = t + j * 256;
    y[(size_t)row * DIM + idx] = f2s((v[j] - mu) * rstd * scale[idx] + bias[idx]);
  }
}

// ---------- no-LDS register GEMM, wide: 128x192 tile, 256 threads, BK=32 ----------
// Wave tile 64x96 (4x6 16x16x32 fragments). Fragments loaded per-lane from
// global (L2-hot), register double-buffered one K-step ahead. No LDS, no
// barriers. MODE 0: qkv split -> Qb/Kb [bh][1024][64], Vtb [bh][64][1024].
// MODE 2: bf16 out + gelu.
template <int MODE>
__global__ __launch_bounds__(256) void gemm_reg192(
    const short* __restrict__ A, const short* __restrict__ Bt,
    const float* __restrict__ bias,
    short* __restrict__ outB,
    short* __restrict__ Qb, short* __restrict__ Kb, short* __restrict__ Vtb,
    int N, int K) {
  const int t = threadIdx.x;
  const int lane = t & 63, w = t >> 6, quad = lane >> 4, l15 = lane & 15;

  const int nbx = gridDim.x;
  const int lid = blockIdx.y * nbx + blockIdx.x;
  const int xcd = lid & 7, local = lid >> 3;
  const int m0 = ((local / nbx) * 8 + xcd) * 128;
  const int n0 = (local % nbx) * 192;
  const int mb = (w & 1) * 64, nb = (w >> 1) * 96;

  // per-lane fragment base pointers (16B-aligned: K multiple of 8, quad*8)
  const short* pa[4];
  const short* pb[6];
#pragma unroll
  for (int mi = 0; mi < 4; ++mi)
    pa[mi] = A + (size_t)(m0 + mb + mi * 16 + l15) * K + quad * 8;
#pragma unroll
  for (int ni = 0; ni < 6; ++ni)
    pb[ni] = Bt + (size_t)(n0 + nb + ni * 16 + l15) * K + quad * 8;

  floatx4 acc[4][6];
#pragma unroll
  for (int mi = 0; mi < 4; ++mi)
#pragma unroll
    for (int ni = 0; ni < 6; ++ni) acc[mi][ni] = zf4();

#define R192_LOAD(AD, BD, KOFF) do { \
  _Pragma("unroll") for (int mi = 0; mi < 4; ++mi) \
    AD[mi] = *(const short8*)(pa[mi] + (KOFF)); \
  _Pragma("unroll") for (int ni = 0; ni < 6; ++ni) \
    BD[ni] = *(const short8*)(pb[ni] + (KOFF)); \
} while (0)

#define R192_MFMA(AD, BD) do { \
  _Pragma("unroll") for (int mi = 0; mi < 4; ++mi) \
    _Pragma("unroll") for (int ni = 0; ni < 6; ++ni) \
      acc[mi][ni] = __builtin_amdgcn_mfma_f32_16x16x32_bf16(AD[mi], BD[ni], acc[mi][ni], 0, 0, 0); \
} while (0)

  short8 a0[4], b0[6], a1[4], b1[6];
  R192_LOAD(a0, b0, 0);
  const int nk = K >> 5;  // 24 (even)
  for (int kt = 0; kt < nk; kt += 2) {
    R192_LOAD(a1, b1, (kt + 1) * 32);      // prefetch next step
    R192_MFMA(a0, b0);
    if (kt + 2 < nk) R192_LOAD(a0, b0, (kt + 2) * 32);
    R192_MFMA(a1, b1);
  }

#pragma unroll
  for (int mi = 0; mi < 4; ++mi) {
    const int row0 = m0 + mb + mi * 16 + quad * 4;
#pragma unroll
    for (int ni = 0; ni < 6; ++ni) {
      const int col = n0 + nb + ni * 16 + l15;
      const float bv = bias[col];
      float v[4];
#pragma unroll
      for (int r = 0; r < 4; ++r) v[r] = acc[mi][ni][r] + bv;
      if (MODE == 0) {
        const int bb = row0 >> 10;
        const int s0 = row0 & 1023;
        if (col < 1536) {
          const int cc = (col < 768) ? col : col - 768;
          const int h = cc >> 6, d = cc & 63;
          short* dst = (col < 768 ? Qb : Kb) + (size_t)(bb * NHEAD + h) * SEQ * HDIM;
#pragma unroll
          for (int r = 0; r < 4; ++r) dst[(size_t)(s0 + r) * HDIM + d] = f2s(v[r]);
        } else {
          const int cc = col - 1536;
          const int h = cc >> 6, d = cc & 63;
          short4v pv;
#pragma unroll
          for (int r = 0; r < 4; ++r) pv[r] = f2s(v[r]);
          *(short4v*)(Vtb + ((size_t)(bb * NHEAD + h) * HDIM + d) * SEQ + s0) = pv;
        }
      } else {
#pragma unroll
        for (int r = 0; r < 4; ++r)
          outB[(size_t)(row0 + r) * N + col] = f2s(gelu_f(v[r]));
      }
    }
  }
}

// ---------- no-LDS register GEMM, narrow: 128x64 tile, 2 waves, BK=32 ----------
// float out + bias + residual (proj, fc2).
__global__ __launch_bounds__(128) void gemm_reg64(
    const short* __restrict__ A, const short* __restrict__ Bt,
    const float* __restrict__ bias, const float* __restrict__ res,
    float* __restrict__ outF, int N, int K) {
  const int t = threadIdx.x;
  const int lane = t & 63, w = t >> 6, quad = lane >> 4, l15 = lane & 15;

  const int nbx = gridDim.x;   // 12
  const int lid = blockIdx.y * nbx + blockIdx.x;
  const int xcd = lid & 7, local = lid >> 3;
  const int m0 = ((local / nbx) * 8 + xcd) * 128;
  const int n0 = (local % nbx) * 64;
  const int mb = w * 64;

  const short* pa[4];
  const short* pb[4];
#pragma unroll
  for (int mi = 0; mi < 4; ++mi)
    pa[mi] = A + (size_t)(m0 + mb + mi * 16 + l15) * K + quad * 8;
#pragma unroll
  for (int ni = 0; ni < 4; ++ni)
    pb[ni] = Bt + (size_t)(n0 + ni * 16 + l15) * K + quad * 8;

  floatx4 acc[4][4];
#pragma unroll
  for (int mi = 0; mi < 4; ++mi)
#pragma unroll
    for (int ni = 0; ni < 4; ++ni) acc[mi][ni] = zf4();

#define R64_LOAD(AD, BD, KOFF) do { \
  _Pragma("unroll") for (int mi = 0; mi < 4; ++mi) \
    AD[mi] = *(const short8*)(pa[mi] + (KOFF)); \
  _Pragma("unroll") for (int ni = 0; ni < 4; ++ni) \
    BD[ni] = *(const short8*)(pb[ni] + (KOFF)); \
} while (0)

#define R64_MFMA(AD, BD) do { \
  _Pragma("unroll") for (int mi = 0; mi < 4; ++mi) \
    _Pragma("unroll") for (int ni = 0; ni < 4; ++ni) \
      acc[mi][ni] = __builtin_amdgcn_mfma_f32_16x16x32_bf16(AD[mi], BD[ni], acc[mi][ni], 0, 0, 0); \
} while (0)

  short8 a0[4], b0[4], a1[4], b1[4];
  R64_LOAD(a0, b0, 0);
  const int nk = K >> 5;  // 24 (proj) / 96 (fc2), even
  for (int kt = 0; kt < nk; kt += 2) {
    R64_LOAD(a1, b1, (kt + 1) * 32);
    R64_MFMA(a0, b0);
    if (kt + 2 < nk) R64_LOAD(a0, b0, (kt + 2) * 32);
    R64_MFMA(a1, b1);
  }

#pragma unroll
  for (int mi = 0; mi < 4; ++mi) {
    const int row0 = m0 + mb + mi * 16 + quad * 4;
#pragma unroll
    for (int ni = 0; ni < 4; ++ni) {
      const int col = n0 + ni * 16 + l15;
      const float bv = bias[col];
#pragma unroll
      for (int r = 0; r < 4; ++r) {
        const size_t idx = (size_t)(row0 + r) * N + col;
        outF[idx] = acc[mi][ni][r] + bv + res[idx];
      }
    }
  }
}

// ---------- attention: S^T = K Q^T, O^T = V^T P^T; KT=64, double-buffered ----------
// (unchanged from the 356us baseline)
__device__ __forceinline__ void stage64(const short* __restrict__ src, int ld,
                                        short* lds, int t) {
  const int lane = t & 63, w = t >> 6;
#pragma unroll
  for (int i = 0; i < 2; ++i) {
    const int S = w * 128 + i * 64 + lane;
    const int r = S >> 3, c0 = S & 7;
    const int c = c0 ^ (r & 7);
    const short* g = src + (size_t)r * ld + c * 8;
    const unsigned off = __builtin_amdgcn_readfirstlane((unsigned)((w * 128 + i * 64) * 16));
    __builtin_amdgcn_global_load_lds(
        (const __attribute__((address_space(1))) void*)g,
        (__attribute__((address_space(3))) void*)((char*)lds + off), 16, 0, 0);
  }
}

__global__ __launch_bounds__(256) void attn_kernel(
    const short* __restrict__ Qb, const short* __restrict__ Kb,
    const short* __restrict__ Vtb, short* __restrict__ o) {
  __shared__ __align__(16) short Ks[2][4096];
  __shared__ __align__(16) short Vts[2][4096];
  __shared__ __align__(16) short Pt[8192];
  const int t = threadIdx.x;
  const int lane = t & 63, w = t >> 6, quad = lane >> 4, l15 = lane & 15;
  const int bh = blockIdx.x;           // 0..95
  const int q0 = blockIdx.y * 128;     // 0..7 tiles
  const size_t qkbase = (size_t)bh * SEQ * HDIM;
  const size_t vbase = (size_t)bh * HDIM * SEQ;
  short* ptw = Pt + w * 2048;
  const float cexp = 0.18033688011f;  // 0.125 * log2(e)

  short8 bq[2][2];
#pragma unroll
  for (int mi = 0; mi < 2; ++mi)
#pragma unroll
    for (int ks = 0; ks < 2; ++ks)
      bq[mi][ks] = *(const short8*)(Qb + qkbase +
                                    (size_t)(q0 + w * 32 + mi * 16 + l15) * HDIM +
                                    ks * 32 + quad * 8);

  floatx4 oacc[4][2];
  float l_acc[2] = {0.f, 0.f};
#pragma unroll
  for (int di = 0; di < 4; ++di)
#pragma unroll
    for (int mi = 0; mi < 2; ++mi) oacc[di][mi] = zf4();

  stage64(Kb + qkbase, HDIM, Ks[0], t);
  stage64(Vtb + vbase, SEQ, Vts[0], t);

  for (int kt = 0; kt < 16; ++kt) {
    __syncthreads();
    const int cur = kt & 1;
    if (kt < 15) {
      stage64(Kb + qkbase + (size_t)(kt + 1) * 64 * HDIM, HDIM, Ks[cur ^ 1], t);
      stage64(Vtb + vbase + (kt + 1) * 64, SEQ, Vts[cur ^ 1], t);
    }

    floatx4 sacc[4][2];
#pragma unroll
    for (int ni = 0; ni < 4; ++ni)
#pragma unroll
      for (int mi = 0; mi < 2; ++mi) sacc[ni][mi] = zf4();
#pragma unroll
    for (int ks = 0; ks < 2; ++ks) {
      short8 ak[4];
#pragma unroll
      for (int ni = 0; ni < 4; ++ni) {
        const int r = ni * 16 + l15;
        ak[ni] = *(const short8*)(Ks[cur] + r * 64 + (((ks * 4 + quad) ^ (r & 7)) * 8));
      }
#pragma unroll
      for (int ni = 0; ni < 4; ++ni)
#pragma unroll
        for (int mi = 0; mi < 2; ++mi)
          sacc[ni][mi] = __builtin_amdgcn_mfma_f32_16x16x32_bf16(ak[ni], bq[mi][ks], sacc[ni][mi], 0, 0, 0);
    }

#pragma unroll
    for (int mi = 0; mi < 2; ++mi) {
      const int row = mi * 16 + l15;
      const int swz = (row & 7) ^ ((row & 8) >> 1);
#pragma unroll
      for (int ni = 0; ni < 4; ++ni) {
        short4v pk;
#pragma unroll
        for (int r = 0; r < 4; ++r) {
          const float p = exp2f(sacc[ni][mi][r] * cexp);
          l_acc[mi] += p;
          pk[r] = f2s(p);
        }
        const int c = ni * 2 + (quad >> 1);
        *(short4v*)(ptw + row * 64 + ((c ^ swz) * 8 + (quad & 1) * 4)) = pk;
      }
    }

#pragma unroll
    for (int ks = 0; ks < 2; ++ks) {
      short8 bp[2];
#pragma unroll
      for (int mi = 0; mi < 2; ++mi) {
        const int row = mi * 16 + l15;
        const int swz = (row & 7) ^ ((row & 8) >> 1);
        bp[mi] = *(const short8*)(ptw + row * 64 + (((ks * 4 + quad) ^ swz) * 8));
      }
      short8 av[4];
#pragma unroll
      for (int di = 0; di < 4; ++di) {
        const int r = di * 16 + l15;
        av[di] = *(const short8*)(Vts[cur] + r * 64 + (((ks * 4 + quad) ^ (r & 7)) * 8));
      }
#pragma unroll
      for (int di = 0; di < 4; ++di)
#pragma unroll
        for (int mi = 0; mi < 2; ++mi)
          oacc[di][mi] = __builtin_amdgcn_mfma_f32_16x16x32_bf16(av[di], bp[mi], oacc[di][mi], 0, 0, 0);
    }
  }

  const int bb = bh / NHEAD, hh = bh % NHEAD;
  float inv[2];
#pragma unroll
  for (int mi = 0; mi < 2; ++mi) {
    float l = l_acc[mi];
    l += __shfl_xor(l, 16, 64);
    l += __shfl_xor(l, 32, 64);
    inv[mi] = 1.0f / l;
  }
#pragma unroll
  for (int di = 0; di < 4; ++di)
#pragma unroll
    for (int mi = 0; mi < 2; ++mi) {
      const int tok = bb * SEQ + q0 + w * 32 + mi * 16 + l15;
      const int d = hh * HDIM + di * 16 + quad * 4;
      short4v ov;
#pragma unroll
      for (int r = 0; r < 4; ++r) ov[r] = f2s(oacc[di][mi][r] * inv[mi]);
      *(short4v*)(o + (size_t)tok * DIM + d) = ov;
    }
}

extern "C" void kernel_launch(void* const* d_in, const int* in_sizes, int n_in,
                              void* d_out, int out_size, void* d_ws, size_t ws_size,
                              hipStream_t stream) {
  const float* x      = (const float*)d_in[0];
  const float* ln1_s  = (const float*)d_in[1];
  const float* ln1_b  = (const float*)d_in[2];
  const float* qkv_w  = (const float*)d_in[3];
  const float* qkv_b  = (const float*)d_in[4];
  const float* proj_w = (const float*)d_in[5];
  const float* proj_b = (const float*)d_in[6];
  const float* ln2_s  = (const float*)d_in[7];
  const float* ln2_b  = (const float*)d_in[8];
  const float* fc1_w  = (const float*)d_in[9];
  const float* fc1_b  = (const float*)d_in[10];
  const float* fc2_w  = (const float*)d_in[11];
  const float* fc2_b  = (const float*)d_in[12];
  float* out = (float*)d_out;

  char* p = (char*)d_ws;
  short* wqt = (short*)p; p += (size_t)(3 * DIM) * DIM * 2;
  short* wpt = (short*)p; p += (size_t)DIM * DIM * 2;
  short* w1t = (short*)p; p += (size_t)HID * DIM * 2;
  short* w2t = (short*)p; p += (size_t)DIM * HID * 2;
  short* y   = (short*)p; p += (size_t)MTOK * DIM * 2;
  short* Qb  = (short*)p; p += (size_t)MTOK * DIM * 2;
  short* Kb  = (short*)p; p += (size_t)MTOK * DIM * 2;
  short* Vtb = (short*)p; p += (size_t)MTOK * DIM * 2;
  float* x1  = (float*)p; p += (size_t)MTOK * DIM * 4;
  short* h   = (short*)p; p += (size_t)MTOK * HID * 2;
  short* obuf = y;
  short* y2   = Qb;

  // prologue: weight transposes + LN1 merged
  pre_kernel<<<6912 + MTOK, 256, 0, stream>>>(qkv_w, wqt, proj_w, wpt, fc1_w, w1t,
                                              fc2_w, w2t, x, ln1_s, ln1_b, y);
  // qkv: 128x192 tiles (2304 = 12 x 192)
  gemm_reg192<0><<<dim3(12, 64), 256, 0, stream>>>(
      y, wqt, qkv_b, nullptr, Qb, Kb, Vtb, 3 * DIM, DIM);
  // attention: grid (bh, qt) for XCD L2 reuse of K/V
  attn_kernel<<<dim3(BATCH * NHEAD, SEQ / 128), 256, 0, stream>>>(Qb, Kb, Vtb, obuf);
  gemm_reg64<<<dim3(12, 64), 128, 0, stream>>>(
      obuf, wpt, proj_b, x, x1, DIM, DIM);
  ln_kernel<<<MTOK, 256, 0, stream>>>(x1, ln2_s, ln2_b, y2);
  // fc1: 128x192 tiles (3072 = 16 x 192)
  gemm_reg192<2><<<dim3(16, 64), 256, 0, stream>>>(
      y2, w1t, fc1_b, h, nullptr, nullptr, nullptr, HID, DIM);
  gemm_reg64<<<dim3(12, 64), 128, 0, stream>>>(
      h, w2t, fc2_b, x1, out, DIM, HID);
}

// Round 9
// 470.464 us; speedup vs baseline: 1.2713x; 1.2713x over previous
//
#include <hip/hip_runtime.h>
#include <hip/hip_bf16.h>
#include <math.h>

// TransformerBlock fp32 in/out; internal bf16 MFMA compute.
// B=8, N=1024, D=768, H=12, hd=64, HIDDEN=3072, EPS=1e-6
//
// R8: hybrid GEMM operand paths. Base = R0 (356us). Single change: A-operand
// fragments load DIRECT from global into registers (per-lane, L1-friendly,
// reg double-buffered with literal indices); B stays LDS-staged exactly as
// R0. Cuts LDS traffic 60->36 KB/K-step (the R0 bottleneck: 22% MfmaUtil ~
// LDS-BW ceiling). R6 showed all-VMEM is worse; this keeps B on the fast
// shared path. attn/pre/ln unchanged from R0.

#define DIM 768
#define SEQ 1024
#define BATCH 8
#define NHEAD 12
#define HDIM 64
#define HID 3072
#define MTOK (BATCH * SEQ)  // 8192

typedef __attribute__((ext_vector_type(8))) short short8;
typedef __attribute__((ext_vector_type(4))) short short4v;
typedef __attribute__((ext_vector_type(4))) float floatx4;

__device__ __forceinline__ short f2s(float x) {
  __hip_bfloat16 h = __float2bfloat16(x);
  return __builtin_bit_cast(short, h);
}
__device__ __forceinline__ float s2f(short s) {
  return __bfloat162float(__builtin_bit_cast(__hip_bfloat16, s));
}
__device__ __forceinline__ floatx4 zf4() {
  floatx4 v; v[0] = v[1] = v[2] = v[3] = 0.f; return v;
}
__device__ __forceinline__ float gelu_f(float x) {
  float z = 0.7978845608028654f * (x + 0.044715f * x * x * x);
  float u = __expf(2.f * z);
  return 0.5f * x * (2.f - 2.f / (u + 1.f));
}

// ---------- merged prologue: 4 weight transposes + LN1 in one launch ----------
__global__ __launch_bounds__(256) void pre_kernel(
    const float* __restrict__ w0, short* __restrict__ o0,
    const float* __restrict__ w1, short* __restrict__ o1,
    const float* __restrict__ w2, short* __restrict__ o2,
    const float* __restrict__ w3, short* __restrict__ o3,
    const float* __restrict__ x, const float* __restrict__ ls,
    const float* __restrict__ lb, short* __restrict__ y) {
  const int id = blockIdx.x;
  const int t = threadIdx.x;
  if (id < 6912) {
    __shared__ float tile[32][33];
    const float* in;
    short* out;
    int K, N, tid;
    if (id < 1728)      { in = w0; out = o0; K = DIM; N = 3 * DIM; tid = id; }
    else if (id < 2304) { in = w1; out = o1; K = DIM; N = DIM;     tid = id - 1728; }
    else if (id < 4608) { in = w2; out = o2; K = DIM; N = HID;     tid = id - 2304; }
    else                { in = w3; out = o3; K = HID; N = DIM;     tid = id - 4608; }
    const int ntx = N >> 5;
    const int n0 = (tid % ntx) * 32, k0 = (tid / ntx) * 32;
    const int tx = t & 31, ty = t >> 5;
#pragma unroll
    for (int i = 0; i < 4; ++i)
      tile[ty + i * 8][tx] = in[(size_t)(k0 + ty + i * 8) * N + n0 + tx];
    __syncthreads();
#pragma unroll
    for (int i = 0; i < 4; ++i)
      out[(size_t)(n0 + ty + i * 8) * K + k0 + tx] = f2s(tile[tx][ty + i * 8]);
  } else {
    const int row = id - 6912;
    const float* xr = x + (size_t)row * DIM;
    float v[3];
    float s1 = 0.f, s2 = 0.f;
#pragma unroll
    for (int j = 0; j < 3; ++j) {
      v[j] = xr[t + j * 256];
      s1 += v[j];
      s2 += v[j] * v[j];
    }
#pragma unroll
    for (int off = 32; off; off >>= 1) {
      s1 += __shfl_down(s1, off, 64);
      s2 += __shfl_down(s2, off, 64);
    }
    __shared__ float r1[4], r2[4], bc[2];
    const int wave = t >> 6, lane = t & 63;
    if (lane == 0) { r1[wave] = s1; r2[wave] = s2; }
    __syncthreads();
    if (t == 0) {
      float S1 = r1[0] + r1[1] + r1[2] + r1[3];
      float S2 = r2[0] + r2[1] + r2[2] + r2[3];
      float mu = S1 * (1.0f / DIM);
      float var = S2 * (1.0f / DIM) - mu * mu;
      bc[0] = mu;
      bc[1] = rsqrtf(fmaxf(var, 0.f) + 1e-6f);
    }
    __syncthreads();
    const float mu = bc[0], rstd = bc[1];
#pragma unroll
    for (int j = 0; j < 3; ++j) {
      const int idx = t + j * 256;
      y[(size_t)row * DIM + idx] = f2s((v[j] - mu) * rstd * ls[idx] + lb[idx]);
    }
  }
}

// ---------- LayerNorm (standalone, for LN2) ----------
__global__ __launch_bounds__(256) void ln_kernel(const float* __restrict__ x,
                                                 const float* __restrict__ scale,
                                                 const float* __restrict__ bias,
                                                 short* __restrict__ y) {
  const int row = blockIdx.x;
  const int t = threadIdx.x;
  const float* xr = x + (size_t)row * DIM;
  float v[3];
  float s1 = 0.f, s2 = 0.f;
#pragma unroll
  for (int j = 0; j < 3; ++j) {
    v[j] = xr[t + j * 256];
    s1 += v[j];
    s2 += v[j] * v[j];
  }
#pragma unroll
  for (int off = 32; off; off >>= 1) {
    s1 += __shfl_down(s1, off, 64);
    s2 += __shfl_down(s2, off, 64);
  }
  __shared__ float r1[4], r2[4], bc[2];
  const int wave = t >> 6, lane = t & 63;
  if (lane == 0) { r1[wave] = s1; r2[wave] = s2; }
  __syncthreads();
  if (t == 0) {
    float S1 = r1[0] + r1[1] + r1[2] + r1[3];
    float S2 = r2[0] + r2[1] + r2[2] + r2[3];
    float mu = S1 * (1.0f / DIM);
    float var = S2 * (1.0f / DIM) - mu * mu;
    bc[0] = mu;
    bc[1] = rsqrtf(fmaxf(var, 0.f) + 1e-6f);
  }
  __syncthreads();
  const float mu = bc[0], rstd = bc[1];
#pragma unroll
  for (int j = 0; j < 3; ++j) {
    const int idx = t + j * 256;
    y[(size_t)row * DIM + idx] = f2s((v[j] - mu) * rstd * scale[idx] + bias[idx]);
  }
}

// ---------- async 16B global->LDS staging, 32-wide rows (4 chunks), xor-swizzled ----------
template <int ROWS, int THREADS>
__device__ __forceinline__ void stageT(const short* __restrict__ src, int ld,
                                       short* lds, int t) {
#pragma unroll
  for (int i = 0; i < (ROWS * 4) / THREADS; ++i) {
    const int S = i * THREADS + t;
    const int row = S >> 2;
    const int chunk = (S & 3) ^ ((row >> 1) & 3);
    const short* g = src + (size_t)row * ld + chunk * 8;
    const unsigned off = __builtin_amdgcn_readfirstlane((unsigned)((S & ~63) * 16));
    __builtin_amdgcn_global_load_lds(
        (const __attribute__((address_space(1))) void*)g,
        (__attribute__((address_space(3))) void*)((char*)lds + off), 16, 0, 0);
  }
}

// ---------- async staging, 64-wide rows (8 chunks), xor-swizzled ----------
template <int ROWS, int THREADS>
__device__ __forceinline__ void stage8(const short* __restrict__ src, int ld,
                                       short* lds, int t) {
#pragma unroll
  for (int i = 0; i < (ROWS * 8) / THREADS; ++i) {
    const int S = i * THREADS + t;
    const int row = S >> 3;
    const int chunk = (S & 7) ^ (row & 7);
    const short* g = src + (size_t)row * ld + chunk * 8;
    const unsigned off = __builtin_amdgcn_readfirstlane((unsigned)((S & ~63) * 16));
    __builtin_amdgcn_global_load_lds(
        (const __attribute__((address_space(1))) void*)g,
        (__attribute__((address_space(3))) void*)((char*)lds + off), 16, 0, 0);
  }
}

// ---------- hybrid MFMA GEMM: 128x192 tile, 256 threads, BK=32; wave 64x96 ----------
// A direct global->reg (double-buffered, literal indices); B staged in LDS.
// MODE 0: qkv split -> Qb/Kb [bh][1024][64], Vtb [bh][64][1024]
// MODE 2: bf16 out + gelu
template <int MODE>
__global__ __launch_bounds__(256) void gemm_w192(
    const short* __restrict__ A, const short* __restrict__ Bt,
    const float* __restrict__ bias,
    short* __restrict__ outB,
    short* __restrict__ Qb, short* __restrict__ Kb, short* __restrict__ Vtb,
    int N, int K) {
  __shared__ __align__(16) short Bsm[2][6144];   // 192 x 32 per buf (24 KB)
  const int t = threadIdx.x;
  const int lane = t & 63, w = t >> 6, quad = lane >> 4, l15 = lane & 15;

  const int nbx = gridDim.x;
  const int lid = blockIdx.y * nbx + blockIdx.x;
  const int xcd = lid & 7, local = lid >> 3;
  const int m0 = ((local / nbx) * 8 + xcd) * 128;
  const int n0 = (local % nbx) * 192;
  const int mb = (w & 1) * 64, nb = (w >> 1) * 96;

  // per-lane A fragment pointers (16B aligned; row contiguous in K)
  const short* pa[4];
#pragma unroll
  for (int mi = 0; mi < 4; ++mi)
    pa[mi] = A + (size_t)(m0 + mb + mi * 16 + l15) * K + quad * 8;

  floatx4 acc[4][6];
#pragma unroll
  for (int mi = 0; mi < 4; ++mi)
#pragma unroll
    for (int ni = 0; ni < 6; ++ni) acc[mi][ni] = zf4();

#define W192_STEP(BUF, AR) do { \
  short8 b_[6]; \
  _Pragma("unroll") for (int ni = 0; ni < 6; ++ni) { \
    const int r = nb + ni * 16 + l15; \
    b_[ni] = *(const short8*)(Bsm[BUF] + r * 32 + ((quad ^ ((r >> 1) & 3)) * 8)); \
  } \
  _Pragma("unroll") for (int mi = 0; mi < 4; ++mi) \
    _Pragma("unroll") for (int ni = 0; ni < 6; ++ni) \
      acc[mi][ni] = __builtin_amdgcn_mfma_f32_16x16x32_bf16(AR[mi], b_[ni], acc[mi][ni], 0, 0, 0); \
} while (0)

  short8 a0[4], a1[4];
#pragma unroll
  for (int mi = 0; mi < 4; ++mi) a0[mi] = *(const short8*)(pa[mi]);
  stageT<192, 256>(Bt + (size_t)n0 * K, K, Bsm[0], t);

  const int nk = K >> 5;  // 24 (even)
  for (int kt = 0; kt < nk; kt += 2) {
    __syncthreads();
    // step kt (buf 0, a0); prefetch kt+1
    stageT<192, 256>(Bt + (size_t)n0 * K + (kt + 1) * 32, K, Bsm[1], t);
#pragma unroll
    for (int mi = 0; mi < 4; ++mi)
      a1[mi] = *(const short8*)(pa[mi] + (kt + 1) * 32);
    W192_STEP(0, a0);
    __syncthreads();
    // step kt+1 (buf 1, a1); prefetch kt+2
    if (kt + 2 < nk) {
      stageT<192, 256>(Bt + (size_t)n0 * K + (kt + 2) * 32, K, Bsm[0], t);
#pragma unroll
      for (int mi = 0; mi < 4; ++mi)
        a0[mi] = *(const short8*)(pa[mi] + (kt + 2) * 32);
    }
    W192_STEP(1, a1);
  }

#pragma unroll
  for (int mi = 0; mi < 4; ++mi) {
    const int row0 = m0 + mb + mi * 16 + quad * 4;
#pragma unroll
    for (int ni = 0; ni < 6; ++ni) {
      const int col = n0 + nb + ni * 16 + l15;
      const float bv = bias[col];
      float v[4];
#pragma unroll
      for (int r = 0; r < 4; ++r) v[r] = acc[mi][ni][r] + bv;
      if (MODE == 0) {
        const int bb = row0 >> 10;
        const int s0 = row0 & 1023;
        if (col < 1536) {
          const int cc = (col < 768) ? col : col - 768;
          const int h = cc >> 6, d = cc & 63;
          short* dst = (col < 768 ? Qb : Kb) + (size_t)(bb * NHEAD + h) * SEQ * HDIM;
#pragma unroll
          for (int r = 0; r < 4; ++r) dst[(size_t)(s0 + r) * HDIM + d] = f2s(v[r]);
        } else {
          const int cc = col - 1536;
          const int h = cc >> 6, d = cc & 63;
          short4v pv;
#pragma unroll
          for (int r = 0; r < 4; ++r) pv[r] = f2s(v[r]);
          *(short4v*)(Vtb + ((size_t)(bb * NHEAD + h) * HDIM + d) * SEQ + s0) = pv;
        }
      } else {
#pragma unroll
        for (int r = 0; r < 4; ++r)
          outB[(size_t)(row0 + r) * N + col] = f2s(gelu_f(v[r]));
      }
    }
  }
}

// ---------- hybrid MFMA GEMM (narrow N=64): 128x64 tile, 2 waves, BK=64 ----------
// A direct global->reg (double-buffered); B staged in LDS.
__global__ __launch_bounds__(128) void gemm_n64(
    const short* __restrict__ A, const short* __restrict__ Bt,
    const float* __restrict__ bias, const float* __restrict__ res,
    float* __restrict__ outF, int N, int K) {
  __shared__ __align__(16) short Bsm[2][4096];   // 64 x 64 per buf (16 KB)
  const int t = threadIdx.x;
  const int lane = t & 63, w = t >> 6, quad = lane >> 4, l15 = lane & 15;

  const int nbx = gridDim.x;   // 12
  const int lid = blockIdx.y * nbx + blockIdx.x;
  const int xcd = lid & 7, local = lid >> 3;
  const int m0 = ((local / nbx) * 8 + xcd) * 128;
  const int n0 = (local % nbx) * 64;
  const int mb = w * 64;

  const short* pa[4];
#pragma unroll
  for (int mi = 0; mi < 4; ++mi)
    pa[mi] = A + (size_t)(m0 + mb + mi * 16 + l15) * K + quad * 8;

  floatx4 acc[4][4];
#pragma unroll
  for (int mi = 0; mi < 4; ++mi)
#pragma unroll
    for (int ni = 0; ni < 4; ++ni) acc[mi][ni] = zf4();

// A regs per K-tile: 8 frags (mi 0..3, ks 0..1), flattened [ks*4+mi]
#define N64_LOADA(AR, KOFF) do { \
  _Pragma("unroll") for (int ks = 0; ks < 2; ++ks) \
    _Pragma("unroll") for (int mi = 0; mi < 4; ++mi) \
      AR[ks * 4 + mi] = *(const short8*)(pa[mi] + (KOFF) + ks * 32); \
} while (0)

#define N64_STEP(BUF, AR) do { \
  _Pragma("unroll") for (int ks = 0; ks < 2; ++ks) { \
    short8 b_[4]; \
    _Pragma("unroll") for (int ni = 0; ni < 4; ++ni) { \
      const int r = ni * 16 + l15; \
      b_[ni] = *(const short8*)(Bsm[BUF] + r * 64 + (((ks * 4 + quad) ^ (r & 7)) * 8)); \
    } \
    _Pragma("unroll") for (int mi = 0; mi < 4; ++mi) \
      _Pragma("unroll") for (int ni = 0; ni < 4; ++ni) \
        acc[mi][ni] = __builtin_amdgcn_mfma_f32_16x16x32_bf16(AR[ks * 4 + mi], b_[ni], acc[mi][ni], 0, 0, 0); \
  } \
} while (0)

  short8 a0[8], a1[8];
  N64_LOADA(a0, 0);
  stage8<64, 128>(Bt + (size_t)n0 * K, K, Bsm[0], t);

  const int nk = K >> 6;  // 12 (proj) / 48 (fc2), even
  for (int kt = 0; kt < nk; kt += 2) {
    __syncthreads();
    stage8<64, 128>(Bt + (size_t)n0 * K + (kt + 1) * 64, K, Bsm[1], t);
    N64_LOADA(a1, (kt + 1) * 64);
    N64_STEP(0, a0);
    __syncthreads();
    if (kt + 2 < nk) {
      stage8<64, 128>(Bt + (size_t)n0 * K + (kt + 2) * 64, K, Bsm[0], t);
      N64_LOADA(a0, (kt + 2) * 64);
    }
    N64_STEP(1, a1);
  }

#pragma unroll
  for (int mi = 0; mi < 4; ++mi) {
    const int row0 = m0 + mb + mi * 16 + quad * 4;
#pragma unroll
    for (int ni = 0; ni < 4; ++ni) {
      const int col = n0 + ni * 16 + l15;
      const float bv = bias[col];
#pragma unroll
      for (int r = 0; r < 4; ++r) {
        const size_t idx = (size_t)(row0 + r) * N + col;
        outF[idx] = acc[mi][ni][r] + bv + res[idx];
      }
    }
  }
}

// ---------- attention: S^T = K Q^T, O^T = V^T P^T; KT=64, double-buffered ----------
// (unchanged from the 356us baseline)
__device__ __forceinline__ void stage64(const short* __restrict__ src, int ld,
                                        short* lds, int t) {
  const int lane = t & 63, w = t >> 6;
#pragma unroll
  for (int i = 0; i < 2; ++i) {
    const int S = w * 128 + i * 64 + lane;
    const int r = S >> 3, c0 = S & 7;
    const int c = c0 ^ (r & 7);
    const short* g = src + (size_t)r * ld + c * 8;
    const unsigned off = __builtin_amdgcn_readfirstlane((unsigned)((w * 128 + i * 64) * 16));
    __builtin_amdgcn_global_load_lds(
        (const __attribute__((address_space(1))) void*)g,
        (__attribute__((address_space(3))) void*)((char*)lds + off), 16, 0, 0);
  }
}

__global__ __launch_bounds__(256) void attn_kernel(
    const short* __restrict__ Qb, const short* __restrict__ Kb,
    const short* __restrict__ Vtb, short* __restrict__ o) {
  __shared__ __align__(16) short Ks[2][4096];
  __shared__ __align__(16) short Vts[2][4096];
  __shared__ __align__(16) short Pt[8192];
  const int t = threadIdx.x;
  const int lane = t & 63, w = t >> 6, quad = lane >> 4, l15 = lane & 15;
  const int bh = blockIdx.x;           // 0..95
  const int q0 = blockIdx.y * 128;     // 0..7 tiles
  const size_t qkbase = (size_t)bh * SEQ * HDIM;
  const size_t vbase = (size_t)bh * HDIM * SEQ;
  short* ptw = Pt + w * 2048;
  const float cexp = 0.18033688011f;  // 0.125 * log2(e)

  short8 bq[2][2];
#pragma unroll
  for (int mi = 0; mi < 2; ++mi)
#pragma unroll
    for (int ks = 0; ks < 2; ++ks)
      bq[mi][ks] = *(const short8*)(Qb + qkbase +
                                    (size_t)(q0 + w * 32 + mi * 16 + l15) * HDIM +
                                    ks * 32 + quad * 8);

  floatx4 oacc[4][2];
  float l_acc[2] = {0.f, 0.f};
#pragma unroll
  for (int di = 0; di < 4; ++di)
#pragma unroll
    for (int mi = 0; mi < 2; ++mi) oacc[di][mi] = zf4();

  stage64(Kb + qkbase, HDIM, Ks[0], t);
  stage64(Vtb + vbase, SEQ, Vts[0], t);

  for (int kt = 0; kt < 16; ++kt) {
    __syncthreads();
    const int cur = kt & 1;
    if (kt < 15) {
      stage64(Kb + qkbase + (size_t)(kt + 1) * 64 * HDIM, HDIM, Ks[cur ^ 1], t);
      stage64(Vtb + vbase + (kt + 1) * 64, SEQ, Vts[cur ^ 1], t);
    }

    floatx4 sacc[4][2];
#pragma unroll
    for (int ni = 0; ni < 4; ++ni)
#pragma unroll
      for (int mi = 0; mi < 2; ++mi) sacc[ni][mi] = zf4();
#pragma unroll
    for (int ks = 0; ks < 2; ++ks) {
      short8 ak[4];
#pragma unroll
      for (int ni = 0; ni < 4; ++ni) {
        const int r = ni * 16 + l15;
        ak[ni] = *(const short8*)(Ks[cur] + r * 64 + (((ks * 4 + quad) ^ (r & 7)) * 8));
      }
#pragma unroll
      for (int ni = 0; ni < 4; ++ni)
#pragma unroll
        for (int mi = 0; mi < 2; ++mi)
          sacc[ni][mi] = __builtin_amdgcn_mfma_f32_16x16x32_bf16(ak[ni], bq[mi][ks], sacc[ni][mi], 0, 0, 0);
    }

#pragma unroll
    for (int mi = 0; mi < 2; ++mi) {
      const int row = mi * 16 + l15;
      const int swz = (row & 7) ^ ((row & 8) >> 1);
#pragma unroll
      for (int ni = 0; ni < 4; ++ni) {
        short4v pk;
#pragma unroll
        for (int r = 0; r < 4; ++r) {
          const float p = exp2f(sacc[ni][mi][r] * cexp);
          l_acc[mi] += p;
          pk[r] = f2s(p);
        }
        const int c = ni * 2 + (quad >> 1);
        *(short4v*)(ptw + row * 64 + ((c ^ swz) * 8 + (quad & 1) * 4)) = pk;
      }
    }

#pragma unroll
    for (int ks = 0; ks < 2; ++ks) {
      short8 bp[2];
#pragma unroll
      for (int mi = 0; mi < 2; ++mi) {
        const int row = mi * 16 + l15;
        const int swz = (row & 7) ^ ((row & 8) >> 1);
        bp[mi] = *(const short8*)(ptw + row * 64 + (((ks * 4 + quad) ^ swz) * 8));
      }
      short8 av[4];
#pragma unroll
      for (int di = 0; di < 4; ++di) {
        const int r = di * 16 + l15;
        av[di] = *(const short8*)(Vts[cur] + r * 64 + (((ks * 4 + quad) ^ (r & 7)) * 8));
      }
#pragma unroll
      for (int di = 0; di < 4; ++di)
#pragma unroll
        for (int mi = 0; mi < 2; ++mi)
          oacc[di][mi] = __builtin_amdgcn_mfma_f32_16x16x32_bf16(av[di], bp[mi], oacc[di][mi], 0, 0, 0);
    }
  }

  const int bb = bh / NHEAD, hh = bh % NHEAD;
  float inv[2];
#pragma unroll
  for (int mi = 0; mi < 2; ++mi) {
    float l = l_acc[mi];
    l += __shfl_xor(l, 16, 64);
    l += __shfl_xor(l, 32, 64);
    inv[mi] = 1.0f / l;
  }
#pragma unroll
  for (int di = 0; di < 4; ++di)
#pragma unroll
    for (int mi = 0; mi < 2; ++mi) {
      const int tok = bb * SEQ + q0 + w * 32 + mi * 16 + l15;
      const int d = hh * HDIM + di * 16 + quad * 4;
      short4v ov;
#pragma unroll
      for (int r = 0; r < 4; ++r) ov[r] = f2s(oacc[di][mi][r] * inv[mi]);
      *(short4v*)(o + (size_t)tok * DIM + d) = ov;
    }
}

extern "C" void kernel_launch(void* const* d_in, const int* in_sizes, int n_in,
                              void* d_out, int out_size, void* d_ws, size_t ws_size,
                              hipStream_t stream) {
  const float* x      = (const float*)d_in[0];
  const float* ln1_s  = (const float*)d_in[1];
  const float* ln1_b  = (const float*)d_in[2];
  const float* qkv_w  = (const float*)d_in[3];
  const float* qkv_b  = (const float*)d_in[4];
  const float* proj_w = (const float*)d_in[5];
  const float* proj_b = (const float*)d_in[6];
  const float* ln2_s  = (const float*)d_in[7];
  const float* ln2_b  = (const float*)d_in[8];
  const float* fc1_w  = (const float*)d_in[9];
  const float* fc1_b  = (const float*)d_in[10];
  const float* fc2_w  = (const float*)d_in[11];
  const float* fc2_b  = (const float*)d_in[12];
  float* out = (float*)d_out;

  char* p = (char*)d_ws;
  short* wqt = (short*)p; p += (size_t)(3 * DIM) * DIM * 2;
  short* wpt = (short*)p; p += (size_t)DIM * DIM * 2;
  short* w1t = (short*)p; p += (size_t)HID * DIM * 2;
  short* w2t = (short*)p; p += (size_t)DIM * HID * 2;
  short* y   = (short*)p; p += (size_t)MTOK * DIM * 2;
  short* Qb  = (short*)p; p += (size_t)MTOK * DIM * 2;
  short* Kb  = (short*)p; p += (size_t)MTOK * DIM * 2;
  short* Vtb = (short*)p; p += (size_t)MTOK * DIM * 2;
  float* x1  = (float*)p; p += (size_t)MTOK * DIM * 4;
  short* h   = (short*)p; p += (size_t)MTOK * HID * 2;
  short* obuf = y;
  short* y2   = Qb;

  // prologue: weight transposes + LN1 merged
  pre_kernel<<<6912 + MTOK, 256, 0, stream>>>(qkv_w, wqt, proj_w, wpt, fc1_w, w1t,
                                              fc2_w, w2t, x, ln1_s, ln1_b, y);
  // qkv: 128x192 tiles (2304 = 12 x 192)
  gemm_w192<0><<<dim3(12, 64), 256, 0, stream>>>(
      y, wqt, qkv_b, nullptr, Qb, Kb, Vtb, 3 * DIM, DIM);
  // attention: grid (bh, qt) for XCD L2 reuse of K/V
  attn_kernel<<<dim3(BATCH * NHEAD, SEQ / 128), 256, 0, stream>>>(Qb, Kb, Vtb, obuf);
  gemm_n64<<<dim3(12, 64), 128, 0, stream>>>(
      obuf, wpt, proj_b, x, x1, DIM, DIM);
  ln_kernel<<<MTOK, 256, 0, stream>>>(x1, ln2_s, ln2_b, y2);
  // fc1: 128x192 tiles (3072 = 16 x 192)
  gemm_w192<2><<<dim3(16, 64), 256, 0, stream>>>(
      y2, w1t, fc1_b, h, nullptr, nullptr, nullptr, HID, DIM);
  gemm_n64<<<dim3(12, 64), 128, 0, stream>>>(
      h, w2t, fc2_b, x1, out, DIM, HID);
}

// Round 12
// 355.963 us; speedup vs baseline: 1.6802x; 1.3217x over previous
//
#include <hip/hip_runtime.h>
#include <hip/hip_bf16.h>
#include <math.h>

// TransformerBlock fp32 in/out; internal bf16 MFMA compute.
// B=8, N=1024, D=768, H=12, hd=64, HIDDEN=3072, EPS=1e-6
//
// R9 (3rd submit; R10 container-failure, R11 acquisition-timeout — never ran).
// GEMMs + attn byte-identical to the 356us R0 baseline (5 GEMM-rework
// rounds all regressed -> structure is a bracketed local optimum).
// Change: pre/ln were launch-bound (15k+8k tiny blocks). Now: 4 transpose
// tiles per block (1728 blocks) + wave-per-row LayerNorm (no LDS, no
// syncthreads; 4 rows/block, 2048 blocks).

#define DIM 768
#define SEQ 1024
#define BATCH 8
#define NHEAD 12
#define HDIM 64
#define HID 3072
#define MTOK (BATCH * SEQ)  // 8192

typedef __attribute__((ext_vector_type(8))) short short8;
typedef __attribute__((ext_vector_type(4))) short short4v;
typedef __attribute__((ext_vector_type(4))) float floatx4;

__device__ __forceinline__ short f2s(float x) {
  __hip_bfloat16 h = __float2bfloat16(x);
  return __builtin_bit_cast(short, h);
}
__device__ __forceinline__ float s2f(short s) {
  return __bfloat162float(__builtin_bit_cast(__hip_bfloat16, s));
}
__device__ __forceinline__ floatx4 zf4() {
  floatx4 v; v[0] = v[1] = v[2] = v[3] = 0.f; return v;
}
__device__ __forceinline__ float gelu_f(float x) {
  float z = 0.7978845608028654f * (x + 0.044715f * x * x * x);
  float u = __expf(2.f * z);
  return 0.5f * x * (2.f - 2.f / (u + 1.f));
}

// ---------- wave-per-row LayerNorm body (row fits one wave: 768 = 12x64) ----------
__device__ __forceinline__ void ln_row(const float* __restrict__ xr,
                                       const float* __restrict__ ls,
                                       const float* __restrict__ lb,
                                       short* __restrict__ yr, int lane) {
  float v[12];
  float s1 = 0.f, s2 = 0.f;
#pragma unroll
  for (int j = 0; j < 12; ++j) {
    v[j] = xr[lane + j * 64];
    s1 += v[j];
    s2 += v[j] * v[j];
  }
#pragma unroll
  for (int off = 32; off; off >>= 1) {
    s1 += __shfl_xor(s1, off, 64);
    s2 += __shfl_xor(s2, off, 64);
  }
  const float mu = s1 * (1.0f / DIM);
  const float var = s2 * (1.0f / DIM) - mu * mu;
  const float rstd = rsqrtf(fmaxf(var, 0.f) + 1e-6f);
#pragma unroll
  for (int j = 0; j < 12; ++j) {
    const int idx = lane + j * 64;
    yr[idx] = f2s((v[j] - mu) * rstd * ls[idx] + lb[idx]);
  }
}

// ---------- merged prologue: weight transposes (4 tiles/block) + LN1 (4 rows/block) ----------
// grid: 1728 transpose blocks (4 x 32x32 tiles each) + 2048 LN blocks (4 rows each)
__global__ __launch_bounds__(256) void pre_kernel(
    const float* __restrict__ w0, short* __restrict__ o0,
    const float* __restrict__ w1, short* __restrict__ o1,
    const float* __restrict__ w2, short* __restrict__ o2,
    const float* __restrict__ w3, short* __restrict__ o3,
    const float* __restrict__ x, const float* __restrict__ ls,
    const float* __restrict__ lb, short* __restrict__ y) {
  const int id = blockIdx.x;
  const int t = threadIdx.x;
  if (id < 1728) {
    __shared__ float tile[32][33];
    const int tx = t & 31, ty = t >> 5;
#pragma unroll
    for (int it = 0; it < 4; ++it) {
      const int gid = id * 4 + it;
      const float* in;
      short* out;
      int K, N, tid;
      if (gid < 1728)      { in = w0; out = o0; K = DIM; N = 3 * DIM; tid = gid; }
      else if (gid < 2304) { in = w1; out = o1; K = DIM; N = DIM;     tid = gid - 1728; }
      else if (gid < 4608) { in = w2; out = o2; K = DIM; N = HID;     tid = gid - 2304; }
      else                 { in = w3; out = o3; K = HID; N = DIM;     tid = gid - 4608; }
      const int ntx = N >> 5;
      const int n0 = (tid % ntx) * 32, k0 = (tid / ntx) * 32;
      if (it) __syncthreads();
#pragma unroll
      for (int i = 0; i < 4; ++i)
        tile[ty + i * 8][tx] = in[(size_t)(k0 + ty + i * 8) * N + n0 + tx];
      __syncthreads();
#pragma unroll
      for (int i = 0; i < 4; ++i)
        out[(size_t)(n0 + ty + i * 8) * K + k0 + tx] = f2s(tile[tx][ty + i * 8]);
    }
  } else {
    const int row = (id - 1728) * 4 + (t >> 6);
    const int lane = t & 63;
    ln_row(x + (size_t)row * DIM, ls, lb, y + (size_t)row * DIM, lane);
  }
}

// ---------- LayerNorm (standalone, for LN2): wave-per-row, 4 rows/block ----------
__global__ __launch_bounds__(256) void ln_kernel(const float* __restrict__ x,
                                                 const float* __restrict__ scale,
                                                 const float* __restrict__ bias,
                                                 short* __restrict__ y) {
  const int row = blockIdx.x * 4 + (threadIdx.x >> 6);
  const int lane = threadIdx.x & 63;
  ln_row(x + (size_t)row * DIM, scale, bias, y + (size_t)row * DIM, lane);
}

// ---------- async 16B global->LDS staging, 32-wide rows (4 chunks), xor-swizzled ----------
template <int ROWS, int THREADS>
__device__ __forceinline__ void stageT(const short* __restrict__ src, int ld,
                                       short* lds, int t) {
#pragma unroll
  for (int i = 0; i < (ROWS * 4) / THREADS; ++i) {
    const int S = i * THREADS + t;
    const int row = S >> 2;
    const int chunk = (S & 3) ^ ((row >> 1) & 3);
    const short* g = src + (size_t)row * ld + chunk * 8;
    const unsigned off = __builtin_amdgcn_readfirstlane((unsigned)((S & ~63) * 16));
    __builtin_amdgcn_global_load_lds(
        (const __attribute__((address_space(1))) void*)g,
        (__attribute__((address_space(3))) void*)((char*)lds + off), 16, 0, 0);
  }
}

// ---------- async staging, 64-wide rows (8 chunks), xor-swizzled ----------
template <int ROWS, int THREADS>
__device__ __forceinline__ void stage8(const short* __restrict__ src, int ld,
                                       short* lds, int t) {
#pragma unroll
  for (int i = 0; i < (ROWS * 8) / THREADS; ++i) {
    const int S = i * THREADS + t;
    const int row = S >> 3;
    const int chunk = (S & 7) ^ (row & 7);
    const short* g = src + (size_t)row * ld + chunk * 8;
    const unsigned off = __builtin_amdgcn_readfirstlane((unsigned)((S & ~63) * 16));
    __builtin_amdgcn_global_load_lds(
        (const __attribute__((address_space(1))) void*)g,
        (__attribute__((address_space(3))) void*)((char*)lds + off), 16, 0, 0);
  }
}

// ---------- wide MFMA GEMM: 128x192 tile, 256 threads, BK=32; wave tile 64x96 ----------
// (byte-identical to the 356us R0 baseline)
// MODE 0: qkv split -> Qb/Kb [bh][1024][64], Vtb [bh][64][1024]
// MODE 2: bf16 out + gelu
template <int MODE>
__global__ __launch_bounds__(256) void gemm_w192(
    const short* __restrict__ A, const short* __restrict__ Bt,
    const float* __restrict__ bias,
    short* __restrict__ outB,
    short* __restrict__ Qb, short* __restrict__ Kb, short* __restrict__ Vtb,
    int N, int K) {
  __shared__ __align__(16) short Asm[2][4096];   // 128 x 32
  __shared__ __align__(16) short Bsm[2][6144];   // 192 x 32
  const int t = threadIdx.x;
  const int lane = t & 63, w = t >> 6, quad = lane >> 4, l15 = lane & 15;

  const int nbx = gridDim.x;
  const int lid = blockIdx.y * nbx + blockIdx.x;
  const int xcd = lid & 7, local = lid >> 3;
  const int m0 = ((local / nbx) * 8 + xcd) * 128;
  const int n0 = (local % nbx) * 192;
  const int mb = (w & 1) * 64, nb = (w >> 1) * 96;

  floatx4 acc[4][6];
#pragma unroll
  for (int mi = 0; mi < 4; ++mi)
#pragma unroll
    for (int ni = 0; ni < 6; ++ni) acc[mi][ni] = zf4();

  stageT<128, 256>(A + (size_t)m0 * K, K, Asm[0], t);
  stageT<192, 256>(Bt + (size_t)n0 * K, K, Bsm[0], t);

  const int nk = K >> 5;
  for (int kt = 0; kt < nk; ++kt) {
    __syncthreads();
    const int cur = kt & 1;
    if (kt + 1 < nk) {
      stageT<128, 256>(A + (size_t)m0 * K + (kt + 1) * 32, K, Asm[cur ^ 1], t);
      stageT<192, 256>(Bt + (size_t)n0 * K + (kt + 1) * 32, K, Bsm[cur ^ 1], t);
    }
    short8 a[4], b[6];
#pragma unroll
    for (int mi = 0; mi < 4; ++mi) {
      const int r = mb + mi * 16 + l15;
      a[mi] = *(const short8*)(Asm[cur] + r * 32 + (quad ^ ((r >> 1) & 3)) * 8);
    }
#pragma unroll
    for (int ni = 0; ni < 6; ++ni) {
      const int r = nb + ni * 16 + l15;
      b[ni] = *(const short8*)(Bsm[cur] + r * 32 + (quad ^ ((r >> 1) & 3)) * 8);
    }
#pragma unroll
    for (int mi = 0; mi < 4; ++mi)
#pragma unroll
      for (int ni = 0; ni < 6; ++ni)
        acc[mi][ni] = __builtin_amdgcn_mfma_f32_16x16x32_bf16(a[mi], b[ni], acc[mi][ni], 0, 0, 0);
  }

#pragma unroll
  for (int mi = 0; mi < 4; ++mi) {
    const int row0 = m0 + mb + mi * 16 + quad * 4;
#pragma unroll
    for (int ni = 0; ni < 6; ++ni) {
      const int col = n0 + nb + ni * 16 + l15;
      const float bv = bias[col];
      float v[4];
#pragma unroll
      for (int r = 0; r < 4; ++r) v[r] = acc[mi][ni][r] + bv;
      if (MODE == 0) {
        const int bb = row0 >> 10;
        const int s0 = row0 & 1023;
        if (col < 1536) {
          const int cc = (col < 768) ? col : col - 768;
          const int h = cc >> 6, d = cc & 63;
          short* dst = (col < 768 ? Qb : Kb) + (size_t)(bb * NHEAD + h) * SEQ * HDIM;
#pragma unroll
          for (int r = 0; r < 4; ++r) dst[(size_t)(s0 + r) * HDIM + d] = f2s(v[r]);
        } else {
          const int cc = col - 1536;
          const int h = cc >> 6, d = cc & 63;
          short4v pv;
#pragma unroll
          for (int r = 0; r < 4; ++r) pv[r] = f2s(v[r]);
          *(short4v*)(Vtb + ((size_t)(bb * NHEAD + h) * HDIM + d) * SEQ + s0) = pv;
        }
      } else {
#pragma unroll
        for (int r = 0; r < 4; ++r)
          outB[(size_t)(row0 + r) * N + col] = f2s(gelu_f(v[r]));
      }
    }
  }
}

// ---------- MFMA GEMM (narrow N=64 tiles): 128x64 tile, 2 waves, BK=64 ----------
// (byte-identical to the 356us R0 baseline)
__global__ __launch_bounds__(128) void gemm_n64(
    const short* __restrict__ A, const short* __restrict__ Bt,
    const float* __restrict__ bias, const float* __restrict__ res,
    float* __restrict__ outF, int N, int K) {
  __shared__ __align__(16) short Asm[2][8192];   // 128 x 64
  __shared__ __align__(16) short Bsm[2][4096];   // 64 x 64
  const int t = threadIdx.x;
  const int lane = t & 63, w = t >> 6, quad = lane >> 4, l15 = lane & 15;

  const int nbx = gridDim.x;   // 12
  const int lid = blockIdx.y * nbx + blockIdx.x;
  const int xcd = lid & 7, local = lid >> 3;
  const int m0 = ((local / nbx) * 8 + xcd) * 128;
  const int n0 = (local % nbx) * 64;
  const int mb = w * 64;

  floatx4 acc[4][4];
#pragma unroll
  for (int mi = 0; mi < 4; ++mi)
#pragma unroll
    for (int ni = 0; ni < 4; ++ni) acc[mi][ni] = zf4();

  stage8<128, 128>(A + (size_t)m0 * K, K, Asm[0], t);
  stage8<64, 128>(Bt + (size_t)n0 * K, K, Bsm[0], t);

  const int nk = K >> 6;
  for (int kt = 0; kt < nk; ++kt) {
    __syncthreads();
    const int cur = kt & 1;
    if (kt + 1 < nk) {
      stage8<128, 128>(A + (size_t)m0 * K + (kt + 1) * 64, K, Asm[cur ^ 1], t);
      stage8<64, 128>(Bt + (size_t)n0 * K + (kt + 1) * 64, K, Bsm[cur ^ 1], t);
    }
#pragma unroll
    for (int ks = 0; ks < 2; ++ks) {
      short8 a[4], b[4];
#pragma unroll
      for (int mi = 0; mi < 4; ++mi) {
        const int r = mb + mi * 16 + l15;
        a[mi] = *(const short8*)(Asm[cur] + r * 64 + (((ks * 4 + quad) ^ (r & 7)) * 8));
      }
#pragma unroll
      for (int ni = 0; ni < 4; ++ni) {
        const int r = ni * 16 + l15;
        b[ni] = *(const short8*)(Bsm[cur] + r * 64 + (((ks * 4 + quad) ^ (r & 7)) * 8));
      }
#pragma unroll
      for (int mi = 0; mi < 4; ++mi)
#pragma unroll
        for (int ni = 0; ni < 4; ++ni)
          acc[mi][ni] = __builtin_amdgcn_mfma_f32_16x16x32_bf16(a[mi], b[ni], acc[mi][ni], 0, 0, 0);
    }
  }

#pragma unroll
  for (int mi = 0; mi < 4; ++mi) {
    const int row0 = m0 + mb + mi * 16 + quad * 4;
#pragma unroll
    for (int ni = 0; ni < 4; ++ni) {
      const int col = n0 + ni * 16 + l15;
      const float bv = bias[col];
#pragma unroll
      for (int r = 0; r < 4; ++r) {
        const size_t idx = (size_t)(row0 + r) * N + col;
        outF[idx] = acc[mi][ni][r] + bv + res[idx];
      }
    }
  }
}

// ---------- attention: S^T = K Q^T, O^T = V^T P^T; KT=64, double-buffered ----------
// (byte-identical to the 356us R0 baseline)
__device__ __forceinline__ void stage64(const short* __restrict__ src, int ld,
                                        short* lds, int t) {
  const int lane = t & 63, w = t >> 6;
#pragma unroll
  for (int i = 0; i < 2; ++i) {
    const int S = w * 128 + i * 64 + lane;
    const int r = S >> 3, c0 = S & 7;
    const int c = c0 ^ (r & 7);
    const short* g = src + (size_t)r * ld + c * 8;
    const unsigned off = __builtin_amdgcn_readfirstlane((unsigned)((w * 128 + i * 64) * 16));
    __builtin_amdgcn_global_load_lds(
        (const __attribute__((address_space(1))) void*)g,
        (__attribute__((address_space(3))) void*)((char*)lds + off), 16, 0, 0);
  }
}

__global__ __launch_bounds__(256) void attn_kernel(
    const short* __restrict__ Qb, const short* __restrict__ Kb,
    const short* __restrict__ Vtb, short* __restrict__ o) {
  __shared__ __align__(16) short Ks[2][4096];
  __shared__ __align__(16) short Vts[2][4096];
  __shared__ __align__(16) short Pt[8192];
  const int t = threadIdx.x;
  const int lane = t & 63, w = t >> 6, quad = lane >> 4, l15 = lane & 15;
  const int bh = blockIdx.x;           // 0..95
  const int q0 = blockIdx.y * 128;     // 0..7 tiles
  const size_t qkbase = (size_t)bh * SEQ * HDIM;
  const size_t vbase = (size_t)bh * HDIM * SEQ;
  short* ptw = Pt + w * 2048;
  const float cexp = 0.18033688011f;  // 0.125 * log2(e)

  short8 bq[2][2];
#pragma unroll
  for (int mi = 0; mi < 2; ++mi)
#pragma unroll
    for (int ks = 0; ks < 2; ++ks)
      bq[mi][ks] = *(const short8*)(Qb + qkbase +
                                    (size_t)(q0 + w * 32 + mi * 16 + l15) * HDIM +
                                    ks * 32 + quad * 8);

  floatx4 oacc[4][2];
  float l_acc[2] = {0.f, 0.f};
#pragma unroll
  for (int di = 0; di < 4; ++di)
#pragma unroll
    for (int mi = 0; mi < 2; ++mi) oacc[di][mi] = zf4();

  stage64(Kb + qkbase, HDIM, Ks[0], t);
  stage64(Vtb + vbase, SEQ, Vts[0], t);

  for (int kt = 0; kt < 16; ++kt) {
    __syncthreads();
    const int cur = kt & 1;
    if (kt < 15) {
      stage64(Kb + qkbase + (size_t)(kt + 1) * 64 * HDIM, HDIM, Ks[cur ^ 1], t);
      stage64(Vtb + vbase + (kt + 1) * 64, SEQ, Vts[cur ^ 1], t);
    }

    floatx4 sacc[4][2];
#pragma unroll
    for (int ni = 0; ni < 4; ++ni)
#pragma unroll
      for (int mi = 0; mi < 2; ++mi) sacc[ni][mi] = zf4();
#pragma unroll
    for (int ks = 0; ks < 2; ++ks) {
      short8 ak[4];
#pragma unroll
      for (int ni = 0; ni < 4; ++ni) {
        const int r = ni * 16 + l15;
        ak[ni] = *(const short8*)(Ks[cur] + r * 64 + (((ks * 4 + quad) ^ (r & 7)) * 8));
      }
#pragma unroll
      for (int ni = 0; ni < 4; ++ni)
#pragma unroll
        for (int mi = 0; mi < 2; ++mi)
          sacc[ni][mi] = __builtin_amdgcn_mfma_f32_16x16x32_bf16(ak[ni], bq[mi][ks], sacc[ni][mi], 0, 0, 0);
    }

#pragma unroll
    for (int mi = 0; mi < 2; ++mi) {
      const int row = mi * 16 + l15;
      const int swz = (row & 7) ^ ((row & 8) >> 1);
#pragma unroll
      for (int ni = 0; ni < 4; ++ni) {
        short4v pk;
#pragma unroll
        for (int r = 0; r < 4; ++r) {
          const float p = exp2f(sacc[ni][mi][r] * cexp);
          l_acc[mi] += p;
          pk[r] = f2s(p);
        }
        const int c = ni * 2 + (quad >> 1);
        *(short4v*)(ptw + row * 64 + ((c ^ swz) * 8 + (quad & 1) * 4)) = pk;
      }
    }

#pragma unroll
    for (int ks = 0; ks < 2; ++ks) {
      short8 bp[2];
#pragma unroll
      for (int mi = 0; mi < 2; ++mi) {
        const int row = mi * 16 + l15;
        const int swz = (row & 7) ^ ((row & 8) >> 1);
        bp[mi] = *(const short8*)(ptw + row * 64 + (((ks * 4 + quad) ^ swz) * 8));
      }
      short8 av[4];
#pragma unroll
      for (int di = 0; di < 4; ++di) {
        const int r = di * 16 + l15;
        av[di] = *(const short8*)(Vts[cur] + r * 64 + (((ks * 4 + quad) ^ (r & 7)) * 8));
      }
#pragma unroll
      for (int di = 0; di < 4; ++di)
#pragma unroll
        for (int mi = 0; mi < 2; ++mi)
          oacc[di][mi] = __builtin_amdgcn_mfma_f32_16x16x32_bf16(av[di], bp[mi], oacc[di][mi], 0, 0, 0);
    }
  }

  const int bb = bh / NHEAD, hh = bh % NHEAD;
  float inv[2];
#pragma unroll
  for (int mi = 0; mi < 2; ++mi) {
    float l = l_acc[mi];
    l += __shfl_xor(l, 16, 64);
    l += __shfl_xor(l, 32, 64);
    inv[mi] = 1.0f / l;
  }
#pragma unroll
  for (int di = 0; di < 4; ++di)
#pragma unroll
    for (int mi = 0; mi < 2; ++mi) {
      const int tok = bb * SEQ + q0 + w * 32 + mi * 16 + l15;
      const int d = hh * HDIM + di * 16 + quad * 4;
      short4v ov;
#pragma unroll
      for (int r = 0; r < 4; ++r) ov[r] = f2s(oacc[di][mi][r] * inv[mi]);
      *(short4v*)(o + (size_t)tok * DIM + d) = ov;
    }
}

extern "C" void kernel_launch(void* const* d_in, const int* in_sizes, int n_in,
                              void* d_out, int out_size, void* d_ws, size_t ws_size,
                              hipStream_t stream) {
  const float* x      = (const float*)d_in[0];
  const float* ln1_s  = (const float*)d_in[1];
  const float* ln1_b  = (const float*)d_in[2];
  const float* qkv_w  = (const float*)d_in[3];
  const float* qkv_b  = (const float*)d_in[4];
  const float* proj_w = (const float*)d_in[5];
  const float* proj_b = (const float*)d_in[6];
  const float* ln2_s  = (const float*)d_in[7];
  const float* ln2_b  = (const float*)d_in[8];
  const float* fc1_w  = (const float*)d_in[9];
  const float* fc1_b  = (const float*)d_in[10];
  const float* fc2_w  = (const float*)d_in[11];
  const float* fc2_b  = (const float*)d_in[12];
  float* out = (float*)d_out;

  char* p = (char*)d_ws;
  short* wqt = (short*)p; p += (size_t)(3 * DIM) * DIM * 2;
  short* wpt = (short*)p; p += (size_t)DIM * DIM * 2;
  short* w1t = (short*)p; p += (size_t)HID * DIM * 2;
  short* w2t = (short*)p; p += (size_t)DIM * HID * 2;
  short* y   = (short*)p; p += (size_t)MTOK * DIM * 2;
  short* Qb  = (short*)p; p += (size_t)MTOK * DIM * 2;
  short* Kb  = (short*)p; p += (size_t)MTOK * DIM * 2;
  short* Vtb = (short*)p; p += (size_t)MTOK * DIM * 2;
  float* x1  = (float*)p; p += (size_t)MTOK * DIM * 4;
  short* h   = (short*)p; p += (size_t)MTOK * HID * 2;
  short* obuf = y;
  short* y2   = Qb;

  // prologue: weight transposes (4 tiles/block) + LN1 (wave-per-row) merged
  pre_kernel<<<1728 + MTOK / 4, 256, 0, stream>>>(qkv_w, wqt, proj_w, wpt, fc1_w, w1t,
                                                  fc2_w, w2t, x, ln1_s, ln1_b, y);
  // qkv: 128x192 tiles (2304 = 12 x 192)
  gemm_w192<0><<<dim3(12, 64), 256, 0, stream>>>(
      y, wqt, qkv_b, nullptr, Qb, Kb, Vtb, 3 * DIM, DIM);
  // attention: grid (bh, qt) for XCD L2 reuse of K/V
  attn_kernel<<<dim3(BATCH * NHEAD, SEQ / 128), 256, 0, stream>>>(Qb, Kb, Vtb, obuf);
  gemm_n64<<<dim3(12, 64), 128, 0, stream>>>(
      obuf, wpt, proj_b, x, x1, DIM, DIM);
  ln_kernel<<<MTOK / 4, 256, 0, stream>>>(x1, ln2_s, ln2_b, y2);
  // fc1: 128x192 tiles (3072 = 16 x 192)
  gemm_w192<2><<<dim3(16, 64), 256, 0, stream>>>(
      y2, w1t, fc1_b, h, nullptr, nullptr, nullptr, HID, DIM);
  gemm_n64<<<dim3(12, 64), 128, 0, stream>>>(
      h, w2t, fc2_b, x1, out, DIM, HID);
}

// Round 14
// 348.772 us; speedup vs baseline: 1.7149x; 1.0206x over previous
//
#include <hip/hip_runtime.h>
#include <hip/hip_bf16.h>
#include <math.h>

// TransformerBlock fp32 in/out; internal bf16 MFMA compute.
// B=8, N=1024, D=768, H=12, hd=64, HIDDEN=3072, EPS=1e-6
//
// R12 (resubmit; prior round hit GPUAcquisitionTimeout, never measured).
// Wide GEMM 128x192 -> 128x128 tiles (m97-verified geometry).
// Theory: w192 wave = 96 AGPR acc + 120 VGPR = 216 regs -> 2 waves/SIMD
// (matches measured 19-22% occupancy); no spare waves to hide the per-K-step
// drain. 128x128 cuts acc to 64 AGPR -> ~3 waves/SIMD. Grid: qkv 18x64,
// fc1 24x64 (well-quantized). Everything else identical to R9-best (355.96).

#define DIM 768
#define SEQ 1024
#define BATCH 8
#define NHEAD 12
#define HDIM 64
#define HID 3072
#define MTOK (BATCH * SEQ)  // 8192

typedef __attribute__((ext_vector_type(8))) short short8;
typedef __attribute__((ext_vector_type(4))) short short4v;
typedef __attribute__((ext_vector_type(4))) float floatx4;

__device__ __forceinline__ short f2s(float x) {
  __hip_bfloat16 h = __float2bfloat16(x);
  return __builtin_bit_cast(short, h);
}
__device__ __forceinline__ float s2f(short s) {
  return __bfloat162float(__builtin_bit_cast(__hip_bfloat16, s));
}
__device__ __forceinline__ floatx4 zf4() {
  floatx4 v; v[0] = v[1] = v[2] = v[3] = 0.f; return v;
}
__device__ __forceinline__ float gelu_f(float x) {
  float z = 0.7978845608028654f * (x + 0.044715f * x * x * x);
  float u = __expf(2.f * z);
  return 0.5f * x * (2.f - 2.f / (u + 1.f));
}

// ---------- wave-per-row LayerNorm body (row fits one wave: 768 = 12x64) ----------
__device__ __forceinline__ void ln_row(const float* __restrict__ xr,
                                       const float* __restrict__ ls,
                                       const float* __restrict__ lb,
                                       short* __restrict__ yr, int lane) {
  float v[12];
  float s1 = 0.f, s2 = 0.f;
#pragma unroll
  for (int j = 0; j < 12; ++j) {
    v[j] = xr[lane + j * 64];
    s1 += v[j];
    s2 += v[j] * v[j];
  }
#pragma unroll
  for (int off = 32; off; off >>= 1) {
    s1 += __shfl_xor(s1, off, 64);
    s2 += __shfl_xor(s2, off, 64);
  }
  const float mu = s1 * (1.0f / DIM);
  const float var = s2 * (1.0f / DIM) - mu * mu;
  const float rstd = rsqrtf(fmaxf(var, 0.f) + 1e-6f);
#pragma unroll
  for (int j = 0; j < 12; ++j) {
    const int idx = lane + j * 64;
    yr[idx] = f2s((v[j] - mu) * rstd * ls[idx] + lb[idx]);
  }
}

// ---------- merged prologue: weight transposes (4 tiles/block) + LN1 (4 rows/block) ----------
__global__ __launch_bounds__(256) void pre_kernel(
    const float* __restrict__ w0, short* __restrict__ o0,
    const float* __restrict__ w1, short* __restrict__ o1,
    const float* __restrict__ w2, short* __restrict__ o2,
    const float* __restrict__ w3, short* __restrict__ o3,
    const float* __restrict__ x, const float* __restrict__ ls,
    const float* __restrict__ lb, short* __restrict__ y) {
  const int id = blockIdx.x;
  const int t = threadIdx.x;
  if (id < 1728) {
    __shared__ float tile[32][33];
    const int tx = t & 31, ty = t >> 5;
#pragma unroll
    for (int it = 0; it < 4; ++it) {
      const int gid = id * 4 + it;
      const float* in;
      short* out;
      int K, N, tid;
      if (gid < 1728)      { in = w0; out = o0; K = DIM; N = 3 * DIM; tid = gid; }
      else if (gid < 2304) { in = w1; out = o1; K = DIM; N = DIM;     tid = gid - 1728; }
      else if (gid < 4608) { in = w2; out = o2; K = DIM; N = HID;     tid = gid - 2304; }
      else                 { in = w3; out = o3; K = HID; N = DIM;     tid = gid - 4608; }
      const int ntx = N >> 5;
      const int n0 = (tid % ntx) * 32, k0 = (tid / ntx) * 32;
      if (it) __syncthreads();
#pragma unroll
      for (int i = 0; i < 4; ++i)
        tile[ty + i * 8][tx] = in[(size_t)(k0 + ty + i * 8) * N + n0 + tx];
      __syncthreads();
#pragma unroll
      for (int i = 0; i < 4; ++i)
        out[(size_t)(n0 + ty + i * 8) * K + k0 + tx] = f2s(tile[tx][ty + i * 8]);
    }
  } else {
    const int row = (id - 1728) * 4 + (t >> 6);
    const int lane = t & 63;
    ln_row(x + (size_t)row * DIM, ls, lb, y + (size_t)row * DIM, lane);
  }
}

// ---------- LayerNorm (standalone, for LN2): wave-per-row, 4 rows/block ----------
__global__ __launch_bounds__(256) void ln_kernel(const float* __restrict__ x,
                                                 const float* __restrict__ scale,
                                                 const float* __restrict__ bias,
                                                 short* __restrict__ y) {
  const int row = blockIdx.x * 4 + (threadIdx.x >> 6);
  const int lane = threadIdx.x & 63;
  ln_row(x + (size_t)row * DIM, scale, bias, y + (size_t)row * DIM, lane);
}

// ---------- async 16B global->LDS staging, 32-wide rows (4 chunks), xor-swizzled ----------
template <int ROWS, int THREADS>
__device__ __forceinline__ void stageT(const short* __restrict__ src, int ld,
                                       short* lds, int t) {
#pragma unroll
  for (int i = 0; i < (ROWS * 4) / THREADS; ++i) {
    const int S = i * THREADS + t;
    const int row = S >> 2;
    const int chunk = (S & 3) ^ ((row >> 1) & 3);
    const short* g = src + (size_t)row * ld + chunk * 8;
    const unsigned off = __builtin_amdgcn_readfirstlane((unsigned)((S & ~63) * 16));
    __builtin_amdgcn_global_load_lds(
        (const __attribute__((address_space(1))) void*)g,
        (__attribute__((address_space(3))) void*)((char*)lds + off), 16, 0, 0);
  }
}

// ---------- async staging, 64-wide rows (8 chunks), xor-swizzled ----------
template <int ROWS, int THREADS>
__device__ __forceinline__ void stage8(const short* __restrict__ src, int ld,
                                       short* lds, int t) {
#pragma unroll
  for (int i = 0; i < (ROWS * 8) / THREADS; ++i) {
    const int S = i * THREADS + t;
    const int row = S >> 3;
    const int chunk = (S & 7) ^ (row & 7);
    const short* g = src + (size_t)row * ld + chunk * 8;
    const unsigned off = __builtin_amdgcn_readfirstlane((unsigned)((S & ~63) * 16));
    __builtin_amdgcn_global_load_lds(
        (const __attribute__((address_space(1))) void*)g,
        (__attribute__((address_space(3))) void*)((char*)lds + off), 16, 0, 0);
  }
}

// ---------- wide MFMA GEMM: 128x128 tile, 256 threads, BK=32; wave tile 64x64 ----------
// m97-verified geometry: acc 4x4 (64 AGPR) -> ~3 waves/SIMD occupancy.
// MODE 0: qkv split -> Qb/Kb [bh][1024][64], Vtb [bh][64][1024]
// MODE 2: bf16 out + gelu
template <int MODE>
__global__ __launch_bounds__(256) void gemm_w128(
    const short* __restrict__ A, const short* __restrict__ Bt,
    const float* __restrict__ bias,
    short* __restrict__ outB,
    short* __restrict__ Qb, short* __restrict__ Kb, short* __restrict__ Vtb,
    int N, int K) {
  __shared__ __align__(16) short Asm[2][4096];   // 128 x 32
  __shared__ __align__(16) short Bsm[2][4096];   // 128 x 32
  const int t = threadIdx.x;
  const int lane = t & 63, w = t >> 6, quad = lane >> 4, l15 = lane & 15;

  const int nbx = gridDim.x;
  const int lid = blockIdx.y * nbx + blockIdx.x;
  const int xcd = lid & 7, local = lid >> 3;
  const int m0 = ((local / nbx) * 8 + xcd) * 128;
  const int n0 = (local % nbx) * 128;
  const int mb = (w & 1) * 64, nb = (w >> 1) * 64;

  floatx4 acc[4][4];
#pragma unroll
  for (int mi = 0; mi < 4; ++mi)
#pragma unroll
    for (int ni = 0; ni < 4; ++ni) acc[mi][ni] = zf4();

  stageT<128, 256>(A + (size_t)m0 * K, K, Asm[0], t);
  stageT<128, 256>(Bt + (size_t)n0 * K, K, Bsm[0], t);

  const int nk = K >> 5;
  for (int kt = 0; kt < nk; ++kt) {
    __syncthreads();
    const int cur = kt & 1;
    if (kt + 1 < nk) {
      stageT<128, 256>(A + (size_t)m0 * K + (kt + 1) * 32, K, Asm[cur ^ 1], t);
      stageT<128, 256>(Bt + (size_t)n0 * K + (kt + 1) * 32, K, Bsm[cur ^ 1], t);
    }
    short8 a[4], b[4];
#pragma unroll
    for (int mi = 0; mi < 4; ++mi) {
      const int r = mb + mi * 16 + l15;
      a[mi] = *(const short8*)(Asm[cur] + r * 32 + (quad ^ ((r >> 1) & 3)) * 8);
    }
#pragma unroll
    for (int ni = 0; ni < 4; ++ni) {
      const int r = nb + ni * 16 + l15;
      b[ni] = *(const short8*)(Bsm[cur] + r * 32 + (quad ^ ((r >> 1) & 3)) * 8);
    }
#pragma unroll
    for (int mi = 0; mi < 4; ++mi)
#pragma unroll
      for (int ni = 0; ni < 4; ++ni)
        acc[mi][ni] = __builtin_amdgcn_mfma_f32_16x16x32_bf16(a[mi], b[ni], acc[mi][ni], 0, 0, 0);
  }

#pragma unroll
  for (int mi = 0; mi < 4; ++mi) {
    const int row0 = m0 + mb + mi * 16 + quad * 4;
#pragma unroll
    for (int ni = 0; ni < 4; ++ni) {
      const int col = n0 + nb + ni * 16 + l15;
      const float bv = bias[col];
      float v[4];
#pragma unroll
      for (int r = 0; r < 4; ++r) v[r] = acc[mi][ni][r] + bv;
      if (MODE == 0) {
        const int bb = row0 >> 10;
        const int s0 = row0 & 1023;
        if (col < 1536) {
          const int cc = (col < 768) ? col : col - 768;
          const int h = cc >> 6, d = cc & 63;
          short* dst = (col < 768 ? Qb : Kb) + (size_t)(bb * NHEAD + h) * SEQ * HDIM;
#pragma unroll
          for (int r = 0; r < 4; ++r) dst[(size_t)(s0 + r) * HDIM + d] = f2s(v[r]);
        } else {
          const int cc = col - 1536;
          const int h = cc >> 6, d = cc & 63;
          short4v pv;
#pragma unroll
          for (int r = 0; r < 4; ++r) pv[r] = f2s(v[r]);
          *(short4v*)(Vtb + ((size_t)(bb * NHEAD + h) * HDIM + d) * SEQ + s0) = pv;
        }
      } else {
#pragma unroll
        for (int r = 0; r < 4; ++r)
          outB[(size_t)(row0 + r) * N + col] = f2s(gelu_f(v[r]));
      }
    }
  }
}

// ---------- MFMA GEMM (narrow N=64 tiles): 128x64 tile, 2 waves, BK=64 ----------
// (byte-identical to the 356us R0 baseline)
__global__ __launch_bounds__(128) void gemm_n64(
    const short* __restrict__ A, const short* __restrict__ Bt,
    const float* __restrict__ bias, const float* __restrict__ res,
    float* __restrict__ outF, int N, int K) {
  __shared__ __align__(16) short Asm[2][8192];   // 128 x 64
  __shared__ __align__(16) short Bsm[2][4096];   // 64 x 64
  const int t = threadIdx.x;
  const int lane = t & 63, w = t >> 6, quad = lane >> 4, l15 = lane & 15;

  const int nbx = gridDim.x;   // 12
  const int lid = blockIdx.y * nbx + blockIdx.x;
  const int xcd = lid & 7, local = lid >> 3;
  const int m0 = ((local / nbx) * 8 + xcd) * 128;
  const int n0 = (local % nbx) * 64;
  const int mb = w * 64;

  floatx4 acc[4][4];
#pragma unroll
  for (int mi = 0; mi < 4; ++mi)
#pragma unroll
    for (int ni = 0; ni < 4; ++ni) acc[mi][ni] = zf4();

  stage8<128, 128>(A + (size_t)m0 * K, K, Asm[0], t);
  stage8<64, 128>(Bt + (size_t)n0 * K, K, Bsm[0], t);

  const int nk = K >> 6;
  for (int kt = 0; kt < nk; ++kt) {
    __syncthreads();
    const int cur = kt & 1;
    if (kt + 1 < nk) {
      stage8<128, 128>(A + (size_t)m0 * K + (kt + 1) * 64, K, Asm[cur ^ 1], t);
      stage8<64, 128>(Bt + (size_t)n0 * K + (kt + 1) * 64, K, Bsm[cur ^ 1], t);
    }
#pragma unroll
    for (int ks = 0; ks < 2; ++ks) {
      short8 a[4], b[4];
#pragma unroll
      for (int mi = 0; mi < 4; ++mi) {
        const int r = mb + mi * 16 + l15;
        a[mi] = *(const short8*)(Asm[cur] + r * 64 + (((ks * 4 + quad) ^ (r & 7)) * 8));
      }
#pragma unroll
      for (int ni = 0; ni < 4; ++ni) {
        const int r = ni * 16 + l15;
        b[ni] = *(const short8*)(Bsm[cur] + r * 64 + (((ks * 4 + quad) ^ (r & 7)) * 8));
      }
#pragma unroll
      for (int mi = 0; mi < 4; ++mi)
#pragma unroll
        for (int ni = 0; ni < 4; ++ni)
          acc[mi][ni] = __builtin_amdgcn_mfma_f32_16x16x32_bf16(a[mi], b[ni], acc[mi][ni], 0, 0, 0);
    }
  }

#pragma unroll
  for (int mi = 0; mi < 4; ++mi) {
    const int row0 = m0 + mb + mi * 16 + quad * 4;
#pragma unroll
    for (int ni = 0; ni < 4; ++ni) {
      const int col = n0 + ni * 16 + l15;
      const float bv = bias[col];
#pragma unroll
      for (int r = 0; r < 4; ++r) {
        const size_t idx = (size_t)(row0 + r) * N + col;
        outF[idx] = acc[mi][ni][r] + bv + res[idx];
      }
    }
  }
}

// ---------- attention: S^T = K Q^T, O^T = V^T P^T; KT=64, double-buffered ----------
// (byte-identical to the 356us R0 baseline)
__device__ __forceinline__ void stage64(const short* __restrict__ src, int ld,
                                        short* lds, int t) {
  const int lane = t & 63, w = t >> 6;
#pragma unroll
  for (int i = 0; i < 2; ++i) {
    const int S = w * 128 + i * 64 + lane;
    const int r = S >> 3, c0 = S & 7;
    const int c = c0 ^ (r & 7);
    const short* g = src + (size_t)r * ld + c * 8;
    const unsigned off = __builtin_amdgcn_readfirstlane((unsigned)((w * 128 + i * 64) * 16));
    __builtin_amdgcn_global_load_lds(
        (const __attribute__((address_space(1))) void*)g,
        (__attribute__((address_space(3))) void*)((char*)lds + off), 16, 0, 0);
  }
}

__global__ __launch_bounds__(256) void attn_kernel(
    const short* __restrict__ Qb, const short* __restrict__ Kb,
    const short* __restrict__ Vtb, short* __restrict__ o) {
  __shared__ __align__(16) short Ks[2][4096];
  __shared__ __align__(16) short Vts[2][4096];
  __shared__ __align__(16) short Pt[8192];
  const int t = threadIdx.x;
  const int lane = t & 63, w = t >> 6, quad = lane >> 4, l15 = lane & 15;
  const int bh = blockIdx.x;           // 0..95
  const int q0 = blockIdx.y * 128;     // 0..7 tiles
  const size_t qkbase = (size_t)bh * SEQ * HDIM;
  const size_t vbase = (size_t)bh * HDIM * SEQ;
  short* ptw = Pt + w * 2048;
  const float cexp = 0.18033688011f;  // 0.125 * log2(e)

  short8 bq[2][2];
#pragma unroll
  for (int mi = 0; mi < 2; ++mi)
#pragma unroll
    for (int ks = 0; ks < 2; ++ks)
      bq[mi][ks] = *(const short8*)(Qb + qkbase +
                                    (size_t)(q0 + w * 32 + mi * 16 + l15) * HDIM +
                                    ks * 32 + quad * 8);

  floatx4 oacc[4][2];
  float l_acc[2] = {0.f, 0.f};
#pragma unroll
  for (int di = 0; di < 4; ++di)
#pragma unroll
    for (int mi = 0; mi < 2; ++mi) oacc[di][mi] = zf4();

  stage64(Kb + qkbase, HDIM, Ks[0], t);
  stage64(Vtb + vbase, SEQ, Vts[0], t);

  for (int kt = 0; kt < 16; ++kt) {
    __syncthreads();
    const int cur = kt & 1;
    if (kt < 15) {
      stage64(Kb + qkbase + (size_t)(kt + 1) * 64 * HDIM, HDIM, Ks[cur ^ 1], t);
      stage64(Vtb + vbase + (kt + 1) * 64, SEQ, Vts[cur ^ 1], t);
    }

    floatx4 sacc[4][2];
#pragma unroll
    for (int ni = 0; ni < 4; ++ni)
#pragma unroll
      for (int mi = 0; mi < 2; ++mi) sacc[ni][mi] = zf4();
#pragma unroll
    for (int ks = 0; ks < 2; ++ks) {
      short8 ak[4];
#pragma unroll
      for (int ni = 0; ni < 4; ++ni) {
        const int r = ni * 16 + l15;
        ak[ni] = *(const short8*)(Ks[cur] + r * 64 + (((ks * 4 + quad) ^ (r & 7)) * 8));
      }
#pragma unroll
      for (int ni = 0; ni < 4; ++ni)
#pragma unroll
        for (int mi = 0; mi < 2; ++mi)
          sacc[ni][mi] = __builtin_amdgcn_mfma_f32_16x16x32_bf16(ak[ni], bq[mi][ks], sacc[ni][mi], 0, 0, 0);
    }

#pragma unroll
    for (int mi = 0; mi < 2; ++mi) {
      const int row = mi * 16 + l15;
      const int swz = (row & 7) ^ ((row & 8) >> 1);
#pragma unroll
      for (int ni = 0; ni < 4; ++ni) {
        short4v pk;
#pragma unroll
        for (int r = 0; r < 4; ++r) {
          const float p = exp2f(sacc[ni][mi][r] * cexp);
          l_acc[mi] += p;
          pk[r] = f2s(p);
        }
        const int c = ni * 2 + (quad >> 1);
        *(short4v*)(ptw + row * 64 + ((c ^ swz) * 8 + (quad & 1) * 4)) = pk;
      }
    }

#pragma unroll
    for (int ks = 0; ks < 2; ++ks) {
      short8 bp[2];
#pragma unroll
      for (int mi = 0; mi < 2; ++mi) {
        const int row = mi * 16 + l15;
        const int swz = (row & 7) ^ ((row & 8) >> 1);
        bp[mi] = *(const short8*)(ptw + row * 64 + (((ks * 4 + quad) ^ swz) * 8));
      }
      short8 av[4];
#pragma unroll
      for (int di = 0; di < 4; ++di) {
        const int r = di * 16 + l15;
        av[di] = *(const short8*)(Vts[cur] + r * 64 + (((ks * 4 + quad) ^ (r & 7)) * 8));
      }
#pragma unroll
      for (int di = 0; di < 4; ++di)
#pragma unroll
        for (int mi = 0; mi < 2; ++mi)
          oacc[di][mi] = __builtin_amdgcn_mfma_f32_16x16x32_bf16(av[di], bp[mi], oacc[di][mi], 0, 0, 0);
    }
  }

  const int bb = bh / NHEAD, hh = bh % NHEAD;
  float inv[2];
#pragma unroll
  for (int mi = 0; mi < 2; ++mi) {
    float l = l_acc[mi];
    l += __shfl_xor(l, 16, 64);
    l += __shfl_xor(l, 32, 64);
    inv[mi] = 1.0f / l;
  }
#pragma unroll
  for (int di = 0; di < 4; ++di)
#pragma unroll
    for (int mi = 0; mi < 2; ++mi) {
      const int tok = bb * SEQ + q0 + w * 32 + mi * 16 + l15;
      const int d = hh * HDIM + di * 16 + quad * 4;
      short4v ov;
#pragma unroll
      for (int r = 0; r < 4; ++r) ov[r] = f2s(oacc[di][mi][r] * inv[mi]);
      *(short4v*)(o + (size_t)tok * DIM + d) = ov;
    }
}

extern "C" void kernel_launch(void* const* d_in, const int* in_sizes, int n_in,
                              void* d_out, int out_size, void* d_ws, size_t ws_size,
                              hipStream_t stream) {
  const float* x      = (const float*)d_in[0];
  const float* ln1_s  = (const float*)d_in[1];
  const float* ln1_b  = (const float*)d_in[2];
  const float* qkv_w  = (const float*)d_in[3];
  const float* qkv_b  = (const float*)d_in[4];
  const float* proj_w = (const float*)d_in[5];
  const float* proj_b = (const float*)d_in[6];
  const float* ln2_s  = (const float*)d_in[7];
  const float* ln2_b  = (const float*)d_in[8];
  const float* fc1_w  = (const float*)d_in[9];
  const float* fc1_b  = (const float*)d_in[10];
  const float* fc2_w  = (const float*)d_in[11];
  const float* fc2_b  = (const float*)d_in[12];
  float* out = (float*)d_out;

  char* p = (char*)d_ws;
  short* wqt = (short*)p; p += (size_t)(3 * DIM) * DIM * 2;
  short* wpt = (short*)p; p += (size_t)DIM * DIM * 2;
  short* w1t = (short*)p; p += (size_t)HID * DIM * 2;
  short* w2t = (short*)p; p += (size_t)DIM * HID * 2;
  short* y   = (short*)p; p += (size_t)MTOK * DIM * 2;
  short* Qb  = (short*)p; p += (size_t)MTOK * DIM * 2;
  short* Kb  = (short*)p; p += (size_t)MTOK * DIM * 2;
  short* Vtb = (short*)p; p += (size_t)MTOK * DIM * 2;
  float* x1  = (float*)p; p += (size_t)MTOK * DIM * 4;
  short* h   = (short*)p; p += (size_t)MTOK * HID * 2;
  short* obuf = y;
  short* y2   = Qb;

  // prologue: weight transposes (4 tiles/block) + LN1 (wave-per-row) merged
  pre_kernel<<<1728 + MTOK / 4, 256, 0, stream>>>(qkv_w, wqt, proj_w, wpt, fc1_w, w1t,
                                                  fc2_w, w2t, x, ln1_s, ln1_b, y);
  // qkv: 128x128 tiles (2304 = 18 x 128)
  gemm_w128<0><<<dim3(18, 64), 256, 0, stream>>>(
      y, wqt, qkv_b, nullptr, Qb, Kb, Vtb, 3 * DIM, DIM);
  // attention: grid (bh, qt) for XCD L2 reuse of K/V
  attn_kernel<<<dim3(BATCH * NHEAD, SEQ / 128), 256, 0, stream>>>(Qb, Kb, Vtb, obuf);
  gemm_n64<<<dim3(12, 64), 128, 0, stream>>>(
      obuf, wpt, proj_b, x, x1, DIM, DIM);
  ln_kernel<<<MTOK / 4, 256, 0, stream>>>(x1, ln2_s, ln2_b, y2);
  // fc1: 128x128 tiles (3072 = 24 x 128)
  gemm_w128<2><<<dim3(24, 64), 256, 0, stream>>>(
      y2, w1t, fc1_b, h, nullptr, nullptr, nullptr, HID, DIM);
  gemm_n64<<<dim3(12, 64), 128, 0, stream>>>(
      h, w2t, fc2_b, x1, out, DIM, HID);
}

// Round 15
// 347.796 us; speedup vs baseline: 1.7197x; 1.0028x over previous
//
#include <hip/hip_runtime.h>
#include <hip/hip_bf16.h>
#include <math.h>

// TransformerBlock fp32 in/out; internal bf16 MFMA compute.
// B=8, N=1024, D=768, H=12, hd=64, HIDDEN=3072, EPS=1e-6
//
// R14: wide GEMM BK 32 -> 64 (12 K-steps instead of 24). Theory: K-step is
// load-latency-bound (~400-500cyc vmcnt drain vs ~100-200cyc compute) and
// occupancy-invariant (R12: occ 19->27% with MfmaUtil flat at 21.5%).
// Halving barrier/drain count and doubling MFMA-per-step lets compute cover
// the latency. Reuses gemm_n64's proven BK=64 swizzle (conflicts=0).
// Everything else identical to R12-best (348.8us).

#define DIM 768
#define SEQ 1024
#define BATCH 8
#define NHEAD 12
#define HDIM 64
#define HID 3072
#define MTOK (BATCH * SEQ)  // 8192

typedef __attribute__((ext_vector_type(8))) short short8;
typedef __attribute__((ext_vector_type(4))) short short4v;
typedef __attribute__((ext_vector_type(4))) float floatx4;

__device__ __forceinline__ short f2s(float x) {
  __hip_bfloat16 h = __float2bfloat16(x);
  return __builtin_bit_cast(short, h);
}
__device__ __forceinline__ float s2f(short s) {
  return __bfloat162float(__builtin_bit_cast(__hip_bfloat16, s));
}
__device__ __forceinline__ floatx4 zf4() {
  floatx4 v; v[0] = v[1] = v[2] = v[3] = 0.f; return v;
}
__device__ __forceinline__ float gelu_f(float x) {
  float z = 0.7978845608028654f * (x + 0.044715f * x * x * x);
  float u = __expf(2.f * z);
  return 0.5f * x * (2.f - 2.f / (u + 1.f));
}

// ---------- wave-per-row LayerNorm body (row fits one wave: 768 = 12x64) ----------
__device__ __forceinline__ void ln_row(const float* __restrict__ xr,
                                       const float* __restrict__ ls,
                                       const float* __restrict__ lb,
                                       short* __restrict__ yr, int lane) {
  float v[12];
  float s1 = 0.f, s2 = 0.f;
#pragma unroll
  for (int j = 0; j < 12; ++j) {
    v[j] = xr[lane + j * 64];
    s1 += v[j];
    s2 += v[j] * v[j];
  }
#pragma unroll
  for (int off = 32; off; off >>= 1) {
    s1 += __shfl_xor(s1, off, 64);
    s2 += __shfl_xor(s2, off, 64);
  }
  const float mu = s1 * (1.0f / DIM);
  const float var = s2 * (1.0f / DIM) - mu * mu;
  const float rstd = rsqrtf(fmaxf(var, 0.f) + 1e-6f);
#pragma unroll
  for (int j = 0; j < 12; ++j) {
    const int idx = lane + j * 64;
    yr[idx] = f2s((v[j] - mu) * rstd * ls[idx] + lb[idx]);
  }
}

// ---------- merged prologue: weight transposes (4 tiles/block) + LN1 (4 rows/block) ----------
__global__ __launch_bounds__(256) void pre_kernel(
    const float* __restrict__ w0, short* __restrict__ o0,
    const float* __restrict__ w1, short* __restrict__ o1,
    const float* __restrict__ w2, short* __restrict__ o2,
    const float* __restrict__ w3, short* __restrict__ o3,
    const float* __restrict__ x, const float* __restrict__ ls,
    const float* __restrict__ lb, short* __restrict__ y) {
  const int id = blockIdx.x;
  const int t = threadIdx.x;
  if (id < 1728) {
    __shared__ float tile[32][33];
    const int tx = t & 31, ty = t >> 5;
#pragma unroll
    for (int it = 0; it < 4; ++it) {
      const int gid = id * 4 + it;
      const float* in;
      short* out;
      int K, N, tid;
      if (gid < 1728)      { in = w0; out = o0; K = DIM; N = 3 * DIM; tid = gid; }
      else if (gid < 2304) { in = w1; out = o1; K = DIM; N = DIM;     tid = gid - 1728; }
      else if (gid < 4608) { in = w2; out = o2; K = DIM; N = HID;     tid = gid - 2304; }
      else                 { in = w3; out = o3; K = HID; N = DIM;     tid = gid - 4608; }
      const int ntx = N >> 5;
      const int n0 = (tid % ntx) * 32, k0 = (tid / ntx) * 32;
      if (it) __syncthreads();
#pragma unroll
      for (int i = 0; i < 4; ++i)
        tile[ty + i * 8][tx] = in[(size_t)(k0 + ty + i * 8) * N + n0 + tx];
      __syncthreads();
#pragma unroll
      for (int i = 0; i < 4; ++i)
        out[(size_t)(n0 + ty + i * 8) * K + k0 + tx] = f2s(tile[tx][ty + i * 8]);
    }
  } else {
    const int row = (id - 1728) * 4 + (t >> 6);
    const int lane = t & 63;
    ln_row(x + (size_t)row * DIM, ls, lb, y + (size_t)row * DIM, lane);
  }
}

// ---------- LayerNorm (standalone, for LN2): wave-per-row, 4 rows/block ----------
__global__ __launch_bounds__(256) void ln_kernel(const float* __restrict__ x,
                                                 const float* __restrict__ scale,
                                                 const float* __restrict__ bias,
                                                 short* __restrict__ y) {
  const int row = blockIdx.x * 4 + (threadIdx.x >> 6);
  const int lane = threadIdx.x & 63;
  ln_row(x + (size_t)row * DIM, scale, bias, y + (size_t)row * DIM, lane);
}

// ---------- async staging, 64-wide rows (8 chunks), xor-swizzled ----------
template <int ROWS, int THREADS>
__device__ __forceinline__ void stage8(const short* __restrict__ src, int ld,
                                       short* lds, int t) {
#pragma unroll
  for (int i = 0; i < (ROWS * 8) / THREADS; ++i) {
    const int S = i * THREADS + t;
    const int row = S >> 3;
    const int chunk = (S & 7) ^ (row & 7);
    const short* g = src + (size_t)row * ld + chunk * 8;
    const unsigned off = __builtin_amdgcn_readfirstlane((unsigned)((S & ~63) * 16));
    __builtin_amdgcn_global_load_lds(
        (const __attribute__((address_space(1))) void*)g,
        (__attribute__((address_space(3))) void*)((char*)lds + off), 16, 0, 0);
  }
}

// ---------- wide MFMA GEMM: 128x128 tile, 256 threads, BK=64; wave tile 64x64 ----------
// 12 K-steps at K=768 (half the barrier/drain count of BK=32); 32 MFMA/wave/step.
// MODE 0: qkv split -> Qb/Kb [bh][1024][64], Vtb [bh][64][1024]
// MODE 2: bf16 out + gelu
template <int MODE>
__global__ __launch_bounds__(256) void gemm_w128(
    const short* __restrict__ A, const short* __restrict__ Bt,
    const float* __restrict__ bias,
    short* __restrict__ outB,
    short* __restrict__ Qb, short* __restrict__ Kb, short* __restrict__ Vtb,
    int N, int K) {
  __shared__ __align__(16) short Asm[2][8192];   // 128 x 64 per buf
  __shared__ __align__(16) short Bsm[2][8192];   // 128 x 64 per buf
  const int t = threadIdx.x;
  const int lane = t & 63, w = t >> 6, quad = lane >> 4, l15 = lane & 15;

  const int nbx = gridDim.x;
  const int lid = blockIdx.y * nbx + blockIdx.x;
  const int xcd = lid & 7, local = lid >> 3;
  const int m0 = ((local / nbx) * 8 + xcd) * 128;
  const int n0 = (local % nbx) * 128;
  const int mb = (w & 1) * 64, nb = (w >> 1) * 64;

  floatx4 acc[4][4];
#pragma unroll
  for (int mi = 0; mi < 4; ++mi)
#pragma unroll
    for (int ni = 0; ni < 4; ++ni) acc[mi][ni] = zf4();

  stage8<128, 256>(A + (size_t)m0 * K, K, Asm[0], t);
  stage8<128, 256>(Bt + (size_t)n0 * K, K, Bsm[0], t);

  const int nk = K >> 6;  // 12
  for (int kt = 0; kt < nk; ++kt) {
    __syncthreads();
    const int cur = kt & 1;
    if (kt + 1 < nk) {
      stage8<128, 256>(A + (size_t)m0 * K + (kt + 1) * 64, K, Asm[cur ^ 1], t);
      stage8<128, 256>(Bt + (size_t)n0 * K + (kt + 1) * 64, K, Bsm[cur ^ 1], t);
    }
#pragma unroll
    for (int ks = 0; ks < 2; ++ks) {
      short8 a[4], b[4];
#pragma unroll
      for (int mi = 0; mi < 4; ++mi) {
        const int r = mb + mi * 16 + l15;
        a[mi] = *(const short8*)(Asm[cur] + r * 64 + (((ks * 4 + quad) ^ (r & 7)) * 8));
      }
#pragma unroll
      for (int ni = 0; ni < 4; ++ni) {
        const int r = nb + ni * 16 + l15;
        b[ni] = *(const short8*)(Bsm[cur] + r * 64 + (((ks * 4 + quad) ^ (r & 7)) * 8));
      }
#pragma unroll
      for (int mi = 0; mi < 4; ++mi)
#pragma unroll
        for (int ni = 0; ni < 4; ++ni)
          acc[mi][ni] = __builtin_amdgcn_mfma_f32_16x16x32_bf16(a[mi], b[ni], acc[mi][ni], 0, 0, 0);
    }
  }

#pragma unroll
  for (int mi = 0; mi < 4; ++mi) {
    const int row0 = m0 + mb + mi * 16 + quad * 4;
#pragma unroll
    for (int ni = 0; ni < 4; ++ni) {
      const int col = n0 + nb + ni * 16 + l15;
      const float bv = bias[col];
      float v[4];
#pragma unroll
      for (int r = 0; r < 4; ++r) v[r] = acc[mi][ni][r] + bv;
      if (MODE == 0) {
        const int bb = row0 >> 10;
        const int s0 = row0 & 1023;
        if (col < 1536) {
          const int cc = (col < 768) ? col : col - 768;
          const int h = cc >> 6, d = cc & 63;
          short* dst = (col < 768 ? Qb : Kb) + (size_t)(bb * NHEAD + h) * SEQ * HDIM;
#pragma unroll
          for (int r = 0; r < 4; ++r) dst[(size_t)(s0 + r) * HDIM + d] = f2s(v[r]);
        } else {
          const int cc = col - 1536;
          const int h = cc >> 6, d = cc & 63;
          short4v pv;
#pragma unroll
          for (int r = 0; r < 4; ++r) pv[r] = f2s(v[r]);
          *(short4v*)(Vtb + ((size_t)(bb * NHEAD + h) * HDIM + d) * SEQ + s0) = pv;
        }
      } else {
#pragma unroll
        for (int r = 0; r < 4; ++r)
          outB[(size_t)(row0 + r) * N + col] = f2s(gelu_f(v[r]));
      }
    }
  }
}

// ---------- MFMA GEMM (narrow N=64 tiles): 128x64 tile, 2 waves, BK=64 ----------
// (byte-identical to the 356us R0 baseline)
__global__ __launch_bounds__(128) void gemm_n64(
    const short* __restrict__ A, const short* __restrict__ Bt,
    const float* __restrict__ bias, const float* __restrict__ res,
    float* __restrict__ outF, int N, int K) {
  __shared__ __align__(16) short Asm[2][8192];   // 128 x 64
  __shared__ __align__(16) short Bsm[2][4096];   // 64 x 64
  const int t = threadIdx.x;
  const int lane = t & 63, w = t >> 6, quad = lane >> 4, l15 = lane & 15;

  const int nbx = gridDim.x;   // 12
  const int lid = blockIdx.y * nbx + blockIdx.x;
  const int xcd = lid & 7, local = lid >> 3;
  const int m0 = ((local / nbx) * 8 + xcd) * 128;
  const int n0 = (local % nbx) * 64;
  const int mb = w * 64;

  floatx4 acc[4][4];
#pragma unroll
  for (int mi = 0; mi < 4; ++mi)
#pragma unroll
    for (int ni = 0; ni < 4; ++ni) acc[mi][ni] = zf4();

  stage8<128, 128>(A + (size_t)m0 * K, K, Asm[0], t);
  stage8<64, 128>(Bt + (size_t)n0 * K, K, Bsm[0], t);

  const int nk = K >> 6;
  for (int kt = 0; kt < nk; ++kt) {
    __syncthreads();
    const int cur = kt & 1;
    if (kt + 1 < nk) {
      stage8<128, 128>(A + (size_t)m0 * K + (kt + 1) * 64, K, Asm[cur ^ 1], t);
      stage8<64, 128>(Bt + (size_t)n0 * K + (kt + 1) * 64, K, Bsm[cur ^ 1], t);
    }
#pragma unroll
    for (int ks = 0; ks < 2; ++ks) {
      short8 a[4], b[4];
#pragma unroll
      for (int mi = 0; mi < 4; ++mi) {
        const int r = mb + mi * 16 + l15;
        a[mi] = *(const short8*)(Asm[cur] + r * 64 + (((ks * 4 + quad) ^ (r & 7)) * 8));
      }
#pragma unroll
      for (int ni = 0; ni < 4; ++ni) {
        const int r = ni * 16 + l15;
        b[ni] = *(const short8*)(Bsm[cur] + r * 64 + (((ks * 4 + quad) ^ (r & 7)) * 8));
      }
#pragma unroll
      for (int mi = 0; mi < 4; ++mi)
#pragma unroll
        for (int ni = 0; ni < 4; ++ni)
          acc[mi][ni] = __builtin_amdgcn_mfma_f32_16x16x32_bf16(a[mi], b[ni], acc[mi][ni], 0, 0, 0);
    }
  }

#pragma unroll
  for (int mi = 0; mi < 4; ++mi) {
    const int row0 = m0 + mb + mi * 16 + quad * 4;
#pragma unroll
    for (int ni = 0; ni < 4; ++ni) {
      const int col = n0 + ni * 16 + l15;
      const float bv = bias[col];
#pragma unroll
      for (int r = 0; r < 4; ++r) {
        const size_t idx = (size_t)(row0 + r) * N + col;
        outF[idx] = acc[mi][ni][r] + bv + res[idx];
      }
    }
  }
}

// ---------- attention: S^T = K Q^T, O^T = V^T P^T; KT=64, double-buffered ----------
// (byte-identical to the 356us R0 baseline)
__device__ __forceinline__ void stage64(const short* __restrict__ src, int ld,
                                        short* lds, int t) {
  const int lane = t & 63, w = t >> 6;
#pragma unroll
  for (int i = 0; i < 2; ++i) {
    const int S = w * 128 + i * 64 + lane;
    const int r = S >> 3, c0 = S & 7;
    const int c = c0 ^ (r & 7);
    const short* g = src + (size_t)r * ld + c * 8;
    const unsigned off = __builtin_amdgcn_readfirstlane((unsigned)((w * 128 + i * 64) * 16));
    __builtin_amdgcn_global_load_lds(
        (const __attribute__((address_space(1))) void*)g,
        (__attribute__((address_space(3))) void*)((char*)lds + off), 16, 0, 0);
  }
}

__global__ __launch_bounds__(256) void attn_kernel(
    const short* __restrict__ Qb, const short* __restrict__ Kb,
    const short* __restrict__ Vtb, short* __restrict__ o) {
  __shared__ __align__(16) short Ks[2][4096];
  __shared__ __align__(16) short Vts[2][4096];
  __shared__ __align__(16) short Pt[8192];
  const int t = threadIdx.x;
  const int lane = t & 63, w = t >> 6, quad = lane >> 4, l15 = lane & 15;
  const int bh = blockIdx.x;           // 0..95
  const int q0 = blockIdx.y * 128;     // 0..7 tiles
  const size_t qkbase = (size_t)bh * SEQ * HDIM;
  const size_t vbase = (size_t)bh * HDIM * SEQ;
  short* ptw = Pt + w * 2048;
  const float cexp = 0.18033688011f;  // 0.125 * log2(e)

  short8 bq[2][2];
#pragma unroll
  for (int mi = 0; mi < 2; ++mi)
#pragma unroll
    for (int ks = 0; ks < 2; ++ks)
      bq[mi][ks] = *(const short8*)(Qb + qkbase +
                                    (size_t)(q0 + w * 32 + mi * 16 + l15) * HDIM +
                                    ks * 32 + quad * 8);

  floatx4 oacc[4][2];
  float l_acc[2] = {0.f, 0.f};
#pragma unroll
  for (int di = 0; di < 4; ++di)
#pragma unroll
    for (int mi = 0; mi < 2; ++mi) oacc[di][mi] = zf4();

  stage64(Kb + qkbase, HDIM, Ks[0], t);
  stage64(Vtb + vbase, SEQ, Vts[0], t);

  for (int kt = 0; kt < 16; ++kt) {
    __syncthreads();
    const int cur = kt & 1;
    if (kt < 15) {
      stage64(Kb + qkbase + (size_t)(kt + 1) * 64 * HDIM, HDIM, Ks[cur ^ 1], t);
      stage64(Vtb + vbase + (kt + 1) * 64, SEQ, Vts[cur ^ 1], t);
    }

    floatx4 sacc[4][2];
#pragma unroll
    for (int ni = 0; ni < 4; ++ni)
#pragma unroll
      for (int mi = 0; mi < 2; ++mi) sacc[ni][mi] = zf4();
#pragma unroll
    for (int ks = 0; ks < 2; ++ks) {
      short8 ak[4];
#pragma unroll
      for (int ni = 0; ni < 4; ++ni) {
        const int r = ni * 16 + l15;
        ak[ni] = *(const short8*)(Ks[cur] + r * 64 + (((ks * 4 + quad) ^ (r & 7)) * 8));
      }
#pragma unroll
      for (int ni = 0; ni < 4; ++ni)
#pragma unroll
        for (int mi = 0; mi < 2; ++mi)
          sacc[ni][mi] = __builtin_amdgcn_mfma_f32_16x16x32_bf16(ak[ni], bq[mi][ks], sacc[ni][mi], 0, 0, 0);
    }

#pragma unroll
    for (int mi = 0; mi < 2; ++mi) {
      const int row = mi * 16 + l15;
      const int swz = (row & 7) ^ ((row & 8) >> 1);
#pragma unroll
      for (int ni = 0; ni < 4; ++ni) {
        short4v pk;
#pragma unroll
        for (int r = 0; r < 4; ++r) {
          const float p = exp2f(sacc[ni][mi][r] * cexp);
          l_acc[mi] += p;
          pk[r] = f2s(p);
        }
        const int c = ni * 2 + (quad >> 1);
        *(short4v*)(ptw + row * 64 + ((c ^ swz) * 8 + (quad & 1) * 4)) = pk;
      }
    }

#pragma unroll
    for (int ks = 0; ks < 2; ++ks) {
      short8 bp[2];
#pragma unroll
      for (int mi = 0; mi < 2; ++mi) {
        const int row = mi * 16 + l15;
        const int swz = (row & 7) ^ ((row & 8) >> 1);
        bp[mi] = *(const short8*)(ptw + row * 64 + (((ks * 4 + quad) ^ swz) * 8));
      }
      short8 av[4];
#pragma unroll
      for (int di = 0; di < 4; ++di) {
        const int r = di * 16 + l15;
        av[di] = *(const short8*)(Vts[cur] + r * 64 + (((ks * 4 + quad) ^ (r & 7)) * 8));
      }
#pragma unroll
      for (int di = 0; di < 4; ++di)
#pragma unroll
        for (int mi = 0; mi < 2; ++mi)
          oacc[di][mi] = __builtin_amdgcn_mfma_f32_16x16x32_bf16(av[di], bp[mi], oacc[di][mi], 0, 0, 0);
    }
  }

  const int bb = bh / NHEAD, hh = bh % NHEAD;
  float inv[2];
#pragma unroll
  for (int mi = 0; mi < 2; ++mi) {
    float l = l_acc[mi];
    l += __shfl_xor(l, 16, 64);
    l += __shfl_xor(l, 32, 64);
    inv[mi] = 1.0f / l;
  }
#pragma unroll
  for (int di = 0; di < 4; ++di)
#pragma unroll
    for (int mi = 0; mi < 2; ++mi) {
      const int tok = bb * SEQ + q0 + w * 32 + mi * 16 + l15;
      const int d = hh * HDIM + di * 16 + quad * 4;
      short4v ov;
#pragma unroll
      for (int r = 0; r < 4; ++r) ov[r] = f2s(oacc[di][mi][r] * inv[mi]);
      *(short4v*)(o + (size_t)tok * DIM + d) = ov;
    }
}

extern "C" void kernel_launch(void* const* d_in, const int* in_sizes, int n_in,
                              void* d_out, int out_size, void* d_ws, size_t ws_size,
                              hipStream_t stream) {
  const float* x      = (const float*)d_in[0];
  const float* ln1_s  = (const float*)d_in[1];
  const float* ln1_b  = (const float*)d_in[2];
  const float* qkv_w  = (const float*)d_in[3];
  const float* qkv_b  = (const float*)d_in[4];
  const float* proj_w = (const float*)d_in[5];
  const float* proj_b = (const float*)d_in[6];
  const float* ln2_s  = (const float*)d_in[7];
  const float* ln2_b  = (const float*)d_in[8];
  const float* fc1_w  = (const float*)d_in[9];
  const float* fc1_b  = (const float*)d_in[10];
  const float* fc2_w  = (const float*)d_in[11];
  const float* fc2_b  = (const float*)d_in[12];
  float* out = (float*)d_out;

  char* p = (char*)d_ws;
  short* wqt = (short*)p; p += (size_t)(3 * DIM) * DIM * 2;
  short* wpt = (short*)p; p += (size_t)DIM * DIM * 2;
  short* w1t = (short*)p; p += (size_t)HID * DIM * 2;
  short* w2t = (short*)p; p += (size_t)DIM * HID * 2;
  short* y   = (short*)p; p += (size_t)MTOK * DIM * 2;
  short* Qb  = (short*)p; p += (size_t)MTOK * DIM * 2;
  short* Kb  = (short*)p; p += (size_t)MTOK * DIM * 2;
  short* Vtb = (short*)p; p += (size_t)MTOK * DIM * 2;
  float* x1  = (float*)p; p += (size_t)MTOK * DIM * 4;
  short* h   = (short*)p; p += (size_t)MTOK * HID * 2;
  short* obuf = y;
  short* y2   = Qb;

  // prologue: weight transposes (4 tiles/block) + LN1 (wave-per-row) merged
  pre_kernel<<<1728 + MTOK / 4, 256, 0, stream>>>(qkv_w, wqt, proj_w, wpt, fc1_w, w1t,
                                                  fc2_w, w2t, x, ln1_s, ln1_b, y);
  // qkv: 128x128 tiles (2304 = 18 x 128)
  gemm_w128<0><<<dim3(18, 64), 256, 0, stream>>>(
      y, wqt, qkv_b, nullptr, Qb, Kb, Vtb, 3 * DIM, DIM);
  // attention: grid (bh, qt) for XCD L2 reuse of K/V
  attn_kernel<<<dim3(BATCH * NHEAD, SEQ / 128), 256, 0, stream>>>(Qb, Kb, Vtb, obuf);
  gemm_n64<<<dim3(12, 64), 128, 0, stream>>>(
      obuf, wpt, proj_b, x, x1, DIM, DIM);
  ln_kernel<<<MTOK / 4, 256, 0, stream>>>(x1, ln2_s, ln2_b, y2);
  // fc1: 128x128 tiles (3072 = 24 x 128)
  gemm_w128<2><<<dim3(24, 64), 256, 0, stream>>>(
      y2, w1t, fc1_b, h, nullptr, nullptr, nullptr, HID, DIM);
  gemm_n64<<<dim3(12, 64), 128, 0, stream>>>(
      h, w2t, fc2_b, x1, out, DIM, HID);
}